// Round 1
// baseline (1963.571 us; speedup 1.0000x reference)
//
#include <hip/hip_runtime.h>
#include <stdint.h>

// Problem constants
#define B_   4
#define S_   2048
#define D_   512
#define H_   8
#define DH_  64
#define V_   100000
#define P_   256
#define N_   (B_*S_)    // 8192 rows
#define NP_  (B_*P_)    // 1024 rows

// ---------------------------------------------------------------------------
// Embedding + n-gram hash:  E[b,s,:] = (byte_emb[byte] + sum_j ngram_emb[j][h_j]) / 7
// h_n = sum_{k=0..n-1} bytes[s-(n-1)+k] * 256^k  (int64 wraparound), floor-mod V.
// NOTE: masked positions (s < n-1) use index 0 (they ADD row 0, not zero!).
// ---------------------------------------------------------------------------
__global__ __launch_bounds__(128) void embed_kernel(
    const int* __restrict__ bytes_seq, const float* __restrict__ byte_emb,
    const float* __restrict__ ngram_emb, float* __restrict__ out)
{
  const int pos = blockIdx.x;           // 0..N_-1
  const int b = pos / S_, s = pos % S_;
  const int* bs = bytes_seq + (size_t)b * S_;

  int w[8];
  #pragma unroll
  for (int k = 0; k < 8; k++) {
    int p = s - 7 + k;
    w[k] = (p >= 0) ? bs[p] : 0;
  }

  int idx[6];
  #pragma unroll
  for (int j = 0; j < 6; j++) {
    const int n = j + 3;
    int id = 0;
    if (s >= n - 1) {
      uint64_t h = 0;
      for (int k = 0; k < n; k++)
        h += (uint64_t)(uint32_t)w[8 - n + k] << (8 * k);
      long long sh = (long long)h;       // int64 wraparound semantics
      long long r = sh % (long long)V_;  // C trunc-mod -> fix to floor-mod
      if (r < 0) r += V_;
      id = (int)r;
    }
    idx[j] = id;
  }

  const int d = threadIdx.x * 4;         // 128 thr x 4 = 512
  float4 acc = *(const float4*)(byte_emb + (size_t)bs[s] * D_ + d);
  #pragma unroll
  for (int j = 0; j < 6; j++) {
    const float4 v = *(const float4*)(ngram_emb + ((size_t)j * V_ + idx[j]) * D_ + d);
    acc.x += v.x; acc.y += v.y; acc.z += v.z; acc.w += v.w;
  }
  const float inv7 = 1.0f / 7.0f;
  acc.x *= inv7; acc.y *= inv7; acc.z *= inv7; acc.w *= inv7;
  *(float4*)(out + (size_t)pos * D_ + d) = acc;
}

// ---------------------------------------------------------------------------
// fp32 GEMM: C[M,N] = A[M,K] @ W[K,N] + bias  (optional relu)
// 128x128 tile, BK=32, 256 threads, 8x8 per thread.
// ---------------------------------------------------------------------------
__global__ __launch_bounds__(256) void gemm_kernel(
    const float* __restrict__ A, const float* __restrict__ W,
    const float* __restrict__ bias, float* __restrict__ C,
    int M, int N, int K, int relu)
{
  __shared__ float As[32][132];   // [k][m], padded (132*4B = 16B-aligned rows)
  __shared__ float Bs[32][132];   // [k][n]
  const int tid = threadIdx.x;
  const int tx = tid & 15, ty = tid >> 4;
  const int bm = blockIdx.y * 128, bn = blockIdx.x * 128;

  float acc[8][8] = {};

  for (int k0 = 0; k0 < K; k0 += 32) {
    // A tile 128x32 via float4 (8 lanes x 16B = 128B per row)
    #pragma unroll
    for (int p = 0; p < 4; p++) {
      int lin = tid + p * 256;          // each lin covers one float4
      int r = lin >> 3;                 // 0..127
      int c = (lin & 7) * 4;            // 0..28
      float4 v = *(const float4*)(A + (size_t)(bm + r) * K + k0 + c);
      As[c + 0][r] = v.x; As[c + 1][r] = v.y;
      As[c + 2][r] = v.z; As[c + 3][r] = v.w;
    }
    // B tile 32x128 via float4
    #pragma unroll
    for (int p = 0; p < 4; p++) {
      int lin = tid + p * 256;
      int r = lin >> 5;                 // 0..31
      int c = (lin & 31) * 4;           // 0..124
      *(float4*)(&Bs[r][c]) = *(const float4*)(W + (size_t)(k0 + r) * N + bn + c);
    }
    __syncthreads();

    #pragma unroll
    for (int k = 0; k < 32; k++) {
      float4 a0 = *(const float4*)(&As[k][ty * 8]);
      float4 a1 = *(const float4*)(&As[k][ty * 8 + 4]);
      float4 b0 = *(const float4*)(&Bs[k][tx * 8]);
      float4 b1 = *(const float4*)(&Bs[k][tx * 8 + 4]);
      float a[8] = {a0.x, a0.y, a0.z, a0.w, a1.x, a1.y, a1.z, a1.w};
      float bb[8] = {b0.x, b0.y, b0.z, b0.w, b1.x, b1.y, b1.z, b1.w};
      #pragma unroll
      for (int i = 0; i < 8; i++)
        #pragma unroll
        for (int j = 0; j < 8; j++)
          acc[i][j] += a[i] * bb[j];
    }
    __syncthreads();
  }

  #pragma unroll
  for (int i = 0; i < 8; i++) {
    const int row = bm + ty * 8 + i;
    #pragma unroll
    for (int j = 0; j < 8; j += 4) {
      const int col = bn + tx * 8 + j;
      float4 v;
      v.x = acc[i][j + 0] + bias[col + 0];
      v.y = acc[i][j + 1] + bias[col + 1];
      v.z = acc[i][j + 2] + bias[col + 2];
      v.w = acc[i][j + 3] + bias[col + 3];
      if (relu) {
        v.x = fmaxf(v.x, 0.f); v.y = fmaxf(v.y, 0.f);
        v.z = fmaxf(v.z, 0.f); v.w = fmaxf(v.w, 0.f);
      }
      *(float4*)(C + (size_t)row * N + col) = v;
    }
  }
}

// ---------------------------------------------------------------------------
// Flash-style attention over [B, L, D] with H=8 heads of DH=64.
// One 256-thread block per (q-tile of 64, head, batch). Streaming softmax.
// K and V share one LDS buffer (kept < 64 KB static LDS).
// ---------------------------------------------------------------------------
__global__ __launch_bounds__(256) void attn_kernel(
    const float* __restrict__ Q, const float* __restrict__ K,
    const float* __restrict__ V, float* __restrict__ O,
    int Lq, int Lk)
{
  __shared__ float Qs[64][65];
  __shared__ float KVs[64][65];
  __shared__ float Ps[64][65];
  __shared__ float red[64][17];
  __shared__ float mrow[64], lrow[64], arow[64];

  const int tid = threadIdx.x;
  const int tx = tid & 15, ty = tid >> 4;
  const int qt = blockIdx.x, h = blockIdx.y, b = blockIdx.z;

  const float* Qp = Q + ((size_t)b * Lq + qt * 64) * D_ + h * DH_;
  const float* Kp = K + (size_t)b * Lk * D_ + h * DH_;
  const float* Vp = V + (size_t)b * Lk * D_ + h * DH_;

  {
    const int r0 = tid >> 6, c = tid & 63;
    #pragma unroll
    for (int p = 0; p < 16; p++) {
      int r = r0 + p * 4;
      Qs[r][c] = Qp[(size_t)r * D_ + c];
    }
  }
  if (tid < 64) { mrow[tid] = -1e30f; lrow[tid] = 0.0f; }

  float oa[4][4] = {};
  float s[4][4];

  for (int kt = 0; kt < Lk; kt += 64) {
    // ---- K tile ----
    {
      const int r0 = tid >> 6, c = tid & 63;
      #pragma unroll
      for (int p = 0; p < 16; p++) {
        int r = r0 + p * 4;
        KVs[r][c] = Kp[(size_t)(kt + r) * D_ + c];
      }
    }
    __syncthreads();                       // sync1: Q/K ready

    #pragma unroll
    for (int i = 0; i < 4; i++)
      #pragma unroll
      for (int j = 0; j < 4; j++) s[i][j] = 0.0f;

    #pragma unroll 4
    for (int d = 0; d < 64; d++) {
      float a0 = Qs[ty*4+0][d], a1 = Qs[ty*4+1][d];
      float a2 = Qs[ty*4+2][d], a3 = Qs[ty*4+3][d];
      float b0 = KVs[tx*4+0][d], b1 = KVs[tx*4+1][d];
      float b2 = KVs[tx*4+2][d], b3 = KVs[tx*4+3][d];
      s[0][0]+=a0*b0; s[0][1]+=a0*b1; s[0][2]+=a0*b2; s[0][3]+=a0*b3;
      s[1][0]+=a1*b0; s[1][1]+=a1*b1; s[1][2]+=a1*b2; s[1][3]+=a1*b3;
      s[2][0]+=a2*b0; s[2][1]+=a2*b1; s[2][2]+=a2*b2; s[2][3]+=a2*b3;
      s[3][0]+=a3*b0; s[3][1]+=a3*b1; s[3][2]+=a3*b2; s[3][3]+=a3*b3;
    }
    #pragma unroll
    for (int i = 0; i < 4; i++) {
      #pragma unroll
      for (int j = 0; j < 4; j++) s[i][j] *= 0.125f;   // DH^-0.5
      red[ty*4+i][tx] = fmaxf(fmaxf(s[i][0], s[i][1]), fmaxf(s[i][2], s[i][3]));
    }
    __syncthreads();                       // sync2: done reading K, maxes ready

    // ---- V tile into same buffer (scores live in regs) + running max ----
    {
      const int r0 = tid >> 6, c = tid & 63;
      #pragma unroll
      for (int p = 0; p < 16; p++) {
        int r = r0 + p * 4;
        KVs[r][c] = Vp[(size_t)(kt + r) * D_ + c];
      }
    }
    if (tid < 64) {
      float tm = red[tid][0];
      #pragma unroll
      for (int j = 1; j < 16; j++) tm = fmaxf(tm, red[tid][j]);
      float mo = mrow[tid];
      float mn = fmaxf(mo, tm);
      arow[tid] = __expf(mo - mn);
      mrow[tid] = mn;
    }
    __syncthreads();                       // sync3: V ready, m/alpha ready

    #pragma unroll
    for (int i = 0; i < 4; i++) {
      const int q = ty * 4 + i;
      const float mn = mrow[q];
      const float al = arow[q];
      float psum = 0.0f;
      #pragma unroll
      for (int j = 0; j < 4; j++) {
        float p = __expf(s[i][j] - mn);
        Ps[q][tx * 4 + j] = p;
        psum += p;
      }
      red[q][tx] = psum;
      #pragma unroll
      for (int j = 0; j < 4; j++) oa[i][j] *= al;
    }
    __syncthreads();                       // sync4: P & partial sums ready

    if (tid < 64) {
      float ls = 0.0f;
      #pragma unroll
      for (int j = 0; j < 16; j++) ls += red[tid][j];
      lrow[tid] = lrow[tid] * arow[tid] + ls;
    }
    #pragma unroll 4
    for (int k = 0; k < 64; k++) {
      float a0 = Ps[ty*4+0][k], a1 = Ps[ty*4+1][k];
      float a2 = Ps[ty*4+2][k], a3 = Ps[ty*4+3][k];
      float b0 = KVs[k][tx*4+0], b1 = KVs[k][tx*4+1];
      float b2 = KVs[k][tx*4+2], b3 = KVs[k][tx*4+3];
      oa[0][0]+=a0*b0; oa[0][1]+=a0*b1; oa[0][2]+=a0*b2; oa[0][3]+=a0*b3;
      oa[1][0]+=a1*b0; oa[1][1]+=a1*b1; oa[1][2]+=a1*b2; oa[1][3]+=a1*b3;
      oa[2][0]+=a2*b0; oa[2][1]+=a2*b1; oa[2][2]+=a2*b2; oa[2][3]+=a2*b3;
      oa[3][0]+=a3*b0; oa[3][1]+=a3*b1; oa[3][2]+=a3*b2; oa[3][3]+=a3*b3;
    }
    __syncthreads();                       // sync5: protect KVs/Ps/red
  }

  float* Op = O + ((size_t)b * Lq + qt * 64) * D_ + h * DH_;
  #pragma unroll
  for (int i = 0; i < 4; i++) {
    const int q = ty * 4 + i;
    const float invl = 1.0f / lrow[q];
    #pragma unroll
    for (int j = 0; j < 4; j++)
      Op[(size_t)q * D_ + tx * 4 + j] = oa[i][j] * invl;
  }
}

// ---------------------------------------------------------------------------
// Fused residual + LayerNorm: out = g * ((a+r) - mean)/sqrt(var+eps) + beta
// ---------------------------------------------------------------------------
__global__ __launch_bounds__(128) void ln_kernel(
    const float* __restrict__ a, const float* __restrict__ r,
    const float* __restrict__ g, const float* __restrict__ be,
    float* __restrict__ out)
{
  const int row = blockIdx.x;
  const int t = threadIdx.x;
  const float4 va = *(const float4*)(a + (size_t)row * D_ + t * 4);
  const float4 vr = *(const float4*)(r + (size_t)row * D_ + t * 4);
  const float x0 = va.x + vr.x, x1 = va.y + vr.y, x2 = va.z + vr.z, x3 = va.w + vr.w;
  float sm = x0 + x1 + x2 + x3;
  float sq = x0*x0 + x1*x1 + x2*x2 + x3*x3;
  #pragma unroll
  for (int off = 32; off > 0; off >>= 1) {
    sm += __shfl_down(sm, off, 64);
    sq += __shfl_down(sq, off, 64);
  }
  __shared__ float s0[2], s1[2];
  if ((t & 63) == 0) { s0[t >> 6] = sm; s1[t >> 6] = sq; }
  __syncthreads();
  const float S  = s0[0] + s0[1];
  const float SQ = s1[0] + s1[1];
  const float mean = S * (1.0f / 512.0f);
  const float var  = SQ * (1.0f / 512.0f) - mean * mean;
  const float inv  = rsqrtf(var + 1e-5f);
  const float4 vg = *(const float4*)(g + t * 4);
  const float4 vb = *(const float4*)(be + t * 4);
  float4 o;
  o.x = vg.x * (x0 - mean) * inv + vb.x;
  o.y = vg.y * (x1 - mean) * inv + vb.y;
  o.z = vg.z * (x2 - mean) * inv + vb.z;
  o.w = vg.w * (x3 - mean) * inv + vb.w;
  *(float4*)(out + (size_t)row * D_ + t * 4) = o;
}

// ---------------------------------------------------------------------------
// Gather patch-boundary rows: out[b,p,:] = x[b, patch_idx[b,p], :]
// ---------------------------------------------------------------------------
__global__ __launch_bounds__(128) void gather_kernel(
    const float* __restrict__ x, const int* __restrict__ pidx,
    float* __restrict__ out)
{
  const int row = blockIdx.x;            // 0..NP_-1
  const int b = row / P_, p = row % P_;
  const int src = pidx[(size_t)b * P_ + p];
  const float* sp = x + ((size_t)b * S_ + src) * D_;
  float* op = out + (size_t)row * D_;
  const int d = threadIdx.x * 4;
  *(float4*)(op + d) = *(const float4*)(sp + d);
}

// ---------------------------------------------------------------------------
extern "C" void kernel_launch(void* const* d_in, const int* in_sizes, int n_in,
                              void* d_out, int out_size, void* d_ws, size_t ws_size,
                              hipStream_t stream) {
  const int*   bytes_seq = (const int*)  d_in[0];
  const int*   patch_idx = (const int*)  d_in[1];
  const float* byte_emb  = (const float*)d_in[2];
  const float* ngram_emb = (const float*)d_in[3];
  const float* sWq = (const float*)d_in[4];  const float* sbq = (const float*)d_in[5];
  const float* sWk = (const float*)d_in[6];  const float* sbk = (const float*)d_in[7];
  const float* sWv = (const float*)d_in[8];  const float* sbv = (const float*)d_in[9];
  const float* sWo = (const float*)d_in[10]; const float* sbo = (const float*)d_in[11];
  const float* ln1g = (const float*)d_in[12]; const float* ln1b = (const float*)d_in[13];
  const float* W1 = (const float*)d_in[14];  const float* b1 = (const float*)d_in[15];
  const float* W2 = (const float*)d_in[16];  const float* b2 = (const float*)d_in[17];
  const float* ln2g = (const float*)d_in[18]; const float* ln2b = (const float*)d_in[19];
  const float* cWq = (const float*)d_in[20]; const float* cbq = (const float*)d_in[21];
  const float* cWk = (const float*)d_in[22]; const float* cbk = (const float*)d_in[23];
  const float* cWv = (const float*)d_in[24]; const float* cbv = (const float*)d_in[25];
  const float* cWo = (const float*)d_in[26]; const float* cbo = (const float*)d_in[27];

  float* ws = (float*)d_ws;
  const size_t NS = (size_t)N_ * D_;     // 4,194,304 floats
  float* E   = ws;                        // embeds / residual
  float* QH  = ws + 1 * NS;               // qh; later HID[0]; later dead
  float* KH  = ws + 2 * NS;               // kh; later HID[1]; later cross-K
  float* VH  = ws + 3 * NS;               // vh; later HID[2]; later cross-V
  float* AT  = ws + 4 * NS;               // attn out; later HID[3]
  float* X1  = ws + 5 * NS;               // post-LN1
  float* X2  = ws + 6 * NS;               // post-LN2
  float* TMP = ws + 7 * NS;               // attn-proj / ffn2 out
  float* HID = QH;                        // [N_, 2048] spans QH..AT
  float* GQ  = ws + 8 * NS;               // [NP_, 512]
  float* CQ  = GQ + (size_t)NP_ * D_;     // [NP_, 512]
  float* CO  = CQ + (size_t)NP_ * D_;     // [NP_, 512]

  const dim3 blk256(256), blk128(128);

  // 1) embeddings
  embed_kernel<<<N_, blk128, 0, stream>>>(bytes_seq, byte_emb, ngram_emb, E);

  // 2) self-attention QKV projections
  gemm_kernel<<<dim3(D_/128, N_/128), blk256, 0, stream>>>(E, sWq, sbq, QH, N_, D_, D_, 0);
  gemm_kernel<<<dim3(D_/128, N_/128), blk256, 0, stream>>>(E, sWk, sbk, KH, N_, D_, D_, 0);
  gemm_kernel<<<dim3(D_/128, N_/128), blk256, 0, stream>>>(E, sWv, sbv, VH, N_, D_, D_, 0);

  // 3) self-attention
  attn_kernel<<<dim3(S_/64, H_, B_), blk256, 0, stream>>>(QH, KH, VH, AT, S_, S_);

  // 4) output projection + LN1
  gemm_kernel<<<dim3(D_/128, N_/128), blk256, 0, stream>>>(AT, sWo, sbo, TMP, N_, D_, D_, 0);
  ln_kernel<<<N_, blk128, 0, stream>>>(E, TMP, ln1g, ln1b, X1);

  // 5) FFN
  gemm_kernel<<<dim3(2048/128, N_/128), blk256, 0, stream>>>(X1, W1, b1, HID, N_, 2048, D_, 1);
  gemm_kernel<<<dim3(D_/128, N_/128), blk256, 0, stream>>>(HID, W2, b2, TMP, N_, D_, 2048, 0);
  ln_kernel<<<N_, blk128, 0, stream>>>(X1, TMP, ln2g, ln2b, X2);

  // 6) cross attention
  gather_kernel<<<NP_, blk128, 0, stream>>>(X2, patch_idx, GQ);
  gemm_kernel<<<dim3(D_/128, NP_/128), blk256, 0, stream>>>(GQ, cWq, cbq, CQ, NP_, D_, D_, 0);
  gemm_kernel<<<dim3(D_/128, N_/128), blk256, 0, stream>>>(X2, cWk, cbk, KH, N_, D_, D_, 0);
  gemm_kernel<<<dim3(D_/128, N_/128), blk256, 0, stream>>>(X2, cWv, cbv, VH, N_, D_, D_, 0);
  attn_kernel<<<dim3(P_/64, H_, B_), blk256, 0, stream>>>(CQ, KH, VH, CO, P_, S_);

  // 7) final projection -> d_out
  gemm_kernel<<<dim3(D_/128, NP_/128), blk256, 0, stream>>>(CO, cWo, cbo, (float*)d_out, NP_, D_, D_, 0);
}

// Round 3
// 462.835 us; speedup vs baseline: 4.2425x; 4.2425x over previous
//
#include <hip/hip_runtime.h>
#include <stdint.h>

#define B_   4
#define S_   2048
#define D_   512
#define H_   8
#define DH_  64
#define V_   100000
#define P_   256
#define N_   (B_*S_)    // 8192 rows
#define NP_  (B_*P_)    // 1024 rows

typedef _Float16 f16;
typedef _Float16 f16x8 __attribute__((ext_vector_type(8)));
typedef float    f32x4 __attribute__((ext_vector_type(4)));

#define MFMA16(a,b,c) __builtin_amdgcn_mfma_f32_16x16x32_f16((a),(b),(c),0,0,0)
#define GLDS16(gp, lp) __builtin_amdgcn_global_load_lds( \
    (const __attribute__((address_space(1))) void*)(gp), \
    (__attribute__((address_space(3))) void*)(lp), 16, 0, 0)

// ---------------------------------------------------------------------------
// Embedding + n-gram hash -> E (fp32) and E16 (f16)
// masked positions (s < n-1) still ADD ngram row 0.
// ---------------------------------------------------------------------------
__global__ __launch_bounds__(128) void embed_kernel(
    const int* __restrict__ bytes_seq, const float* __restrict__ byte_emb,
    const float* __restrict__ ngram_emb, float* __restrict__ out,
    f16* __restrict__ out16)
{
  const int pos = blockIdx.x;           // 0..N_-1
  const int b = pos / S_, s = pos % S_;
  const int* bs = bytes_seq + (size_t)b * S_;

  int w[8];
  #pragma unroll
  for (int k = 0; k < 8; k++) {
    int p = s - 7 + k;
    w[k] = (p >= 0) ? bs[p] : 0;
  }

  int idx[6];
  #pragma unroll
  for (int j = 0; j < 6; j++) {
    const int n = j + 3;
    int id = 0;
    if (s >= n - 1) {
      uint64_t h = 0;
      for (int k = 0; k < n; k++)
        h += (uint64_t)(uint32_t)w[8 - n + k] << (8 * k);
      long long sh = (long long)h;       // int64 wraparound semantics
      long long r = sh % (long long)V_;  // trunc-mod to floor-mod
      if (r < 0) r += V_;
      id = (int)r;
    }
    idx[j] = id;
  }

  const int d = threadIdx.x * 4;
  float4 acc = *(const float4*)(byte_emb + (size_t)bs[s] * D_ + d);
  #pragma unroll
  for (int j = 0; j < 6; j++) {
    const float4 v = *(const float4*)(ngram_emb + ((size_t)j * V_ + idx[j]) * D_ + d);
    acc.x += v.x; acc.y += v.y; acc.z += v.z; acc.w += v.w;
  }
  const float inv7 = 1.0f / 7.0f;
  acc.x *= inv7; acc.y *= inv7; acc.z *= inv7; acc.w *= inv7;
  *(float4*)(out + (size_t)pos * D_ + d) = acc;
  f16* o16 = out16 + (size_t)pos * D_ + d;
  o16[0] = (f16)acc.x; o16[1] = (f16)acc.y; o16[2] = (f16)acc.z; o16[3] = (f16)acc.w;
}

// ---------------------------------------------------------------------------
// Weight conversion: fp32 [K][N] -> f16 [N][K]  (10 jobs, one launch)
// ---------------------------------------------------------------------------
struct WJobs {
  const float* src[10];
  f16* dst[10];
  int K[10], N[10], tiles[10];
};

__global__ __launch_bounds__(256) void wconv_kernel(WJobs jobs)
{
  const int j = blockIdx.y;
  const int tile = blockIdx.x;
  if (tile >= jobs.tiles[j]) return;
  const int K = jobs.K[j], N = jobs.N[j];
  const int ntiles = N >> 5;
  const int kt = (tile / ntiles) << 5, nt = (tile % ntiles) << 5;
  __shared__ float T[32][33];
  const int t = threadIdx.x;
  const float* src = jobs.src[j];
  #pragma unroll
  for (int p = 0; p < 4; p++) {
    int lin = t + p * 256;
    int rr = lin >> 5, cc = lin & 31;
    T[rr][cc] = src[(size_t)(kt + rr) * N + nt + cc];
  }
  __syncthreads();
  f16* dst = jobs.dst[j];
  #pragma unroll
  for (int p = 0; p < 4; p++) {
    int lin = t + p * 256;
    int rr = lin >> 5, cc = lin & 31;
    dst[(size_t)(nt + rr) * K + kt + cc] = (f16)T[cc][rr];
  }
}

// ---------------------------------------------------------------------------
// f16 MFMA GEMM: C[M,N] = A[M,K] @ W[K,N] + bias, W given TRANSPOSED Bt[N][K].
// 128x128 tile, BK=32, 4 waves (2x2), 4x4 16x16 frags/wave, double-buffered
// LDS staged via global_load_lds width 16 (m97 structure, 2-phase).
// ---------------------------------------------------------------------------
template<typename OutT, int RELU>
__global__ __launch_bounds__(256) void gemm_f16(
    const f16* __restrict__ A, const f16* __restrict__ Bt,
    const float* __restrict__ bias, OutT* __restrict__ C,
    int M, int N, int K)
{
  __shared__ __align__(16) f16 As[2][128 * 32];
  __shared__ __align__(16) f16 Bs[2][128 * 32];
  const int tid = threadIdx.x;
  const int l = tid & 63;
  const int lo4 = l & 15, hi2 = l >> 4;
  const int w = tid >> 6;
  const int wr = w >> 1, wc = w & 1;
  const int bm = blockIdx.y * 128, bn = blockIdx.x * 128;

  f32x4 acc[4][4];
  #pragma unroll
  for (int m = 0; m < 4; m++)
    #pragma unroll
    for (int n = 0; n < 4; n++) acc[m][n] = (f32x4){0.f, 0.f, 0.f, 0.f};

  const int nt = K >> 5;

  // stage tile 0
  #pragma unroll
  for (int i = 0; i < 2; i++) {
    int c = i * 256 + tid;
    GLDS16(A  + (size_t)(bm + (c >> 2)) * K + (c & 3) * 8, &As[0][c * 8]);
    GLDS16(Bt + (size_t)(bn + (c >> 2)) * K + (c & 3) * 8, &Bs[0][c * 8]);
  }

  for (int t = 0; t < nt; t++) {
    __syncthreads();                       // stage(t) complete, other buf free
    const int cur = t & 1;
    if (t + 1 < nt) {
      const int k0 = (t + 1) << 5;
      #pragma unroll
      for (int i = 0; i < 2; i++) {
        int c = i * 256 + tid;
        GLDS16(A  + (size_t)(bm + (c >> 2)) * K + k0 + (c & 3) * 8, &As[cur ^ 1][c * 8]);
        GLDS16(Bt + (size_t)(bn + (c >> 2)) * K + k0 + (c & 3) * 8, &Bs[cur ^ 1][c * 8]);
      }
    }
    f16x8 af[4], bf[4];
    const f16* pa = &As[cur][(wr * 64 + lo4) * 32 + hi2 * 8];
    const f16* pb = &Bs[cur][(wc * 64 + lo4) * 32 + hi2 * 8];
    #pragma unroll
    for (int m = 0; m < 4; m++) af[m] = *(const f16x8*)(pa + m * 16 * 32);
    #pragma unroll
    for (int n = 0; n < 4; n++) bf[n] = *(const f16x8*)(pb + n * 16 * 32);
    #pragma unroll
    for (int m = 0; m < 4; m++)
      #pragma unroll
      for (int n = 0; n < 4; n++)
        acc[m][n] = MFMA16(af[m], bf[n], acc[m][n]);
  }

  // epilogue: C row = bm+wr*64+m*16+hi2*4+j, col = bn+wc*64+n*16+lo4
  #pragma unroll
  for (int n = 0; n < 4; n++) {
    const int col = bn + wc * 64 + n * 16 + lo4;
    const float bcol = bias[col];
    #pragma unroll
    for (int m = 0; m < 4; m++) {
      const int row0 = bm + wr * 64 + m * 16 + hi2 * 4;
      #pragma unroll
      for (int j = 0; j < 4; j++) {
        float v = acc[m][n][j] + bcol;
        if (RELU) v = fmaxf(v, 0.f);
        C[(size_t)(row0 + j) * N + col] = (OutT)v;
      }
    }
  }
}

// ---------------------------------------------------------------------------
// f16 MFMA flash attention. H=8, DH=64, Lk=S_=2048.
// Block: 256 thr (4 waves); each wave owns 16 Q-rows of a 64-row Q tile.
// KV tiles of 64 staged in shared LDS: K [64][72] row-major, V^T [64][72].
// P transposed through wave-private padded LDS buffer.
// ---------------------------------------------------------------------------
__global__ __launch_bounds__(256) void attn_f16(
    const f16* __restrict__ Q, const f16* __restrict__ K,
    const f16* __restrict__ V, f16* __restrict__ O, int Lq)
{
  __shared__ __align__(16) f16 Ks[64][72];
  __shared__ __align__(16) f16 Vt[64][72];
  __shared__ __align__(16) f16 Pw[4][16][72];

  const int tid = threadIdx.x;
  const int w = tid >> 6, l = tid & 63;
  const int lo4 = l & 15, hi2 = l >> 4;
  const int qt = blockIdx.x, h = blockIdx.y, b = blockIdx.z;

  // Q frags (A-layout: row = lane&15, k = (lane>>4)*8 + i)
  const int qrow = qt * 64 + w * 16 + lo4;
  const f16* Qp = Q + ((size_t)(b * Lq + qrow)) * D_ + h * DH_ + hi2 * 8;
  f16x8 qf[2];
  qf[0] = *(const f16x8*)(Qp);
  qf[1] = *(const f16x8*)(Qp + 32);

  const f16* Kb = K + ((size_t)b * S_) * D_ + h * DH_;
  const f16* Vb = V + ((size_t)b * S_) * D_ + h * DH_;

  float m_run[4], l_run[4];
  f32x4 oacc[4];
  #pragma unroll
  for (int j = 0; j < 4; j++) { m_run[j] = -1e30f; l_run[j] = 0.f; }
  #pragma unroll
  for (int df = 0; df < 4; df++) oacc[df] = (f32x4){0.f, 0.f, 0.f, 0.f};

  const int r0 = tid >> 3;   // staging row within 32-row half
  const int c8 = tid & 7;    // 8-element column chunk

  for (int kt = 0; kt < S_; kt += 64) {
    // reg-stage K/V (issue before barrier: overlaps prev tile tail)
    f16x8 kreg[2], vreg[2];
    #pragma unroll
    for (int i = 0; i < 2; i++) {
      int row = i * 32 + r0;
      kreg[i] = *(const f16x8*)(Kb + (size_t)(kt + row) * D_ + c8 * 8);
      vreg[i] = *(const f16x8*)(Vb + (size_t)(kt + row) * D_ + c8 * 8);
    }
    __syncthreads();                       // prev tile fully consumed
    #pragma unroll
    for (int i = 0; i < 2; i++) {
      int row = i * 32 + r0;
      *(f16x8*)(&Ks[row][c8 * 8]) = kreg[i];
      #pragma unroll
      for (int jj = 0; jj < 8; jj++)
        Vt[c8 * 8 + jj][row] = vreg[i][jj];   // transpose V into LDS
    }
    __syncthreads();                       // K/V visible

    // S = Q K^T * scale   (C-layout: row q = hi2*4+j, col kv = lo4 + 16nf)
    f32x4 sacc[4];
    #pragma unroll
    for (int nf = 0; nf < 4; nf++) {
      f32x4 s = (f32x4){0.f, 0.f, 0.f, 0.f};
      #pragma unroll
      for (int ch = 0; ch < 2; ch++) {
        f16x8 kf = *(const f16x8*)(&Ks[nf * 16 + lo4][ch * 32 + hi2 * 8]);
        s = MFMA16(qf[ch], kf, s);
      }
      sacc[nf] = s * 0.125f;
    }

    // online softmax (rows j live in regs; reduce across the 16-lane group)
    float mx[4];
    #pragma unroll
    for (int j = 0; j < 4; j++) {
      float m0 = fmaxf(fmaxf(sacc[0][j], sacc[1][j]), fmaxf(sacc[2][j], sacc[3][j]));
      #pragma unroll
      for (int off = 1; off < 16; off <<= 1)
        m0 = fmaxf(m0, __shfl_xor(m0, off, 64));
      mx[j] = m0;
    }
    float alpha[4], rs[4];
    #pragma unroll
    for (int j = 0; j < 4; j++) {
      float mn = fmaxf(m_run[j], mx[j]);
      alpha[j] = __expf(m_run[j] - mn);
      m_run[j] = mn;
      rs[j] = 0.f;
    }
    #pragma unroll
    for (int nf = 0; nf < 4; nf++) {
      #pragma unroll
      for (int j = 0; j < 4; j++) {
        float p = __expf(sacc[nf][j] - m_run[j]);
        rs[j] += p;
        Pw[w][hi2 * 4 + j][nf * 16 + lo4] = (f16)p;   // wave-private
      }
    }
    #pragma unroll
    for (int j = 0; j < 4; j++) {
      float r = rs[j];
      #pragma unroll
      for (int off = 1; off < 16; off <<= 1)
        r += __shfl_xor(r, off, 64);
      l_run[j] = l_run[j] * alpha[j] + r;
    }
    #pragma unroll
    for (int df = 0; df < 4; df++)
      #pragma unroll
      for (int j = 0; j < 4; j++)
        oacc[df][j] *= alpha[j];

    // O += P V   (A = P from Pw, B = V^T rows)
    f16x8 pa[2];
    #pragma unroll
    for (int ch2 = 0; ch2 < 2; ch2++)
      pa[ch2] = *(const f16x8*)(&Pw[w][lo4][ch2 * 32 + hi2 * 8]);
    #pragma unroll
    for (int df = 0; df < 4; df++) {
      #pragma unroll
      for (int ch2 = 0; ch2 < 2; ch2++) {
        f16x8 vf = *(const f16x8*)(&Vt[df * 16 + lo4][ch2 * 32 + hi2 * 8]);
        oacc[df] = MFMA16(pa[ch2], vf, oacc[df]);
      }
    }
  }

  #pragma unroll
  for (int df = 0; df < 4; df++) {
    const int col = h * DH_ + df * 16 + lo4;
    #pragma unroll
    for (int j = 0; j < 4; j++) {
      const int row = qt * 64 + w * 16 + hi2 * 4 + j;
      O[(size_t)(b * Lq + row) * D_ + col] = (f16)(oacc[df][j] / l_run[j]);
    }
  }
}

// ---------------------------------------------------------------------------
// Fused residual + LayerNorm: out = g*((a+r)-mean)/sqrt(var+eps)+beta
// writes fp32 and f16 copies
// ---------------------------------------------------------------------------
__global__ __launch_bounds__(128) void ln_kernel(
    const float* __restrict__ a, const float* __restrict__ r,
    const float* __restrict__ g, const float* __restrict__ be,
    float* __restrict__ out, f16* __restrict__ out16)
{
  const int row = blockIdx.x;
  const int t = threadIdx.x;
  const float4 va = *(const float4*)(a + (size_t)row * D_ + t * 4);
  const float4 vr = *(const float4*)(r + (size_t)row * D_ + t * 4);
  const float x0 = va.x + vr.x, x1 = va.y + vr.y, x2 = va.z + vr.z, x3 = va.w + vr.w;
  float sm = x0 + x1 + x2 + x3;
  float sq = x0*x0 + x1*x1 + x2*x2 + x3*x3;
  #pragma unroll
  for (int off = 32; off > 0; off >>= 1) {
    sm += __shfl_down(sm, off, 64);
    sq += __shfl_down(sq, off, 64);
  }
  __shared__ float s0[2], s1[2];
  if ((t & 63) == 0) { s0[t >> 6] = sm; s1[t >> 6] = sq; }
  __syncthreads();
  const float Sm = s0[0] + s0[1];
  const float Sq = s1[0] + s1[1];
  const float mean = Sm * (1.0f / 512.0f);
  const float var  = Sq * (1.0f / 512.0f) - mean * mean;
  const float inv  = rsqrtf(var + 1e-5f);
  const float4 vg = *(const float4*)(g + t * 4);
  const float4 vb = *(const float4*)(be + t * 4);
  float4 o;
  o.x = vg.x * (x0 - mean) * inv + vb.x;
  o.y = vg.y * (x1 - mean) * inv + vb.y;
  o.z = vg.z * (x2 - mean) * inv + vb.z;
  o.w = vg.w * (x3 - mean) * inv + vb.w;
  *(float4*)(out + (size_t)row * D_ + t * 4) = o;
  f16* o16 = out16 + (size_t)row * D_ + t * 4;
  o16[0] = (f16)o.x; o16[1] = (f16)o.y; o16[2] = (f16)o.z; o16[3] = (f16)o.w;
}

// ---------------------------------------------------------------------------
// Gather patch rows (f16)
// ---------------------------------------------------------------------------
__global__ __launch_bounds__(128) void gather_f16(
    const f16* __restrict__ x, const int* __restrict__ pidx,
    f16* __restrict__ out)
{
  const int row = blockIdx.x;
  const int b = row / P_, p = row % P_;
  const int src = pidx[(size_t)b * P_ + p];
  const uint2* sp = (const uint2*)(x + ((size_t)b * S_ + src) * D_);
  uint2* op = (uint2*)(out + (size_t)row * D_);
  op[threadIdx.x] = sp[threadIdx.x];
}

// ---------------------------------------------------------------------------
extern "C" void kernel_launch(void* const* d_in, const int* in_sizes, int n_in,
                              void* d_out, int out_size, void* d_ws, size_t ws_size,
                              hipStream_t stream) {
  const int*   bytes_seq = (const int*)  d_in[0];
  const int*   patch_idx = (const int*)  d_in[1];
  const float* byte_emb  = (const float*)d_in[2];
  const float* ngram_emb = (const float*)d_in[3];
  const float* sWq = (const float*)d_in[4];  const float* sbq = (const float*)d_in[5];
  const float* sWk = (const float*)d_in[6];  const float* sbk = (const float*)d_in[7];
  const float* sWv = (const float*)d_in[8];  const float* sbv = (const float*)d_in[9];
  const float* sWo = (const float*)d_in[10]; const float* sbo = (const float*)d_in[11];
  const float* ln1g = (const float*)d_in[12]; const float* ln1b = (const float*)d_in[13];
  const float* W1 = (const float*)d_in[14];  const float* b1 = (const float*)d_in[15];
  const float* W2 = (const float*)d_in[16];  const float* b2 = (const float*)d_in[17];
  const float* ln2g = (const float*)d_in[18]; const float* ln2b = (const float*)d_in[19];
  const float* cWq = (const float*)d_in[20]; const float* cbq = (const float*)d_in[21];
  const float* cWk = (const float*)d_in[22]; const float* cbk = (const float*)d_in[23];
  const float* cWv = (const float*)d_in[24]; const float* cbv = (const float*)d_in[25];
  const float* cWo = (const float*)d_in[26]; const float* cbo = (const float*)d_in[27];

  char* base = (char*)d_ws;
  const size_t MB = 1u << 20;
  float* E    = (float*)(base + 0 * MB);     // 16 MB
  float* TMP  = (float*)(base + 16 * MB);    // 16 MB
  float* X1   = (float*)(base + 32 * MB);    // 16 MB
  f16* E16    = (f16*)(base + 48 * MB);      // 8 MB
  f16* X116   = (f16*)(base + 56 * MB);      // 8 MB
  f16* X216   = (f16*)(base + 64 * MB);      // 8 MB
  f16* QH16   = (f16*)(base + 72 * MB);      // 8 MB, part of HID16 region
  f16* KH16   = (f16*)(base + 80 * MB);      // 8 MB, part of HID16 region
  f16* VH16   = (f16*)(base + 88 * MB);      // 8 MB, part of HID16 region
  f16* AT16   = (f16*)(base + 96 * MB);      // 8 MB, part of HID16 region
  f16* HID16  = QH16;                        // [8192][2048] f16 = 32 MB (72..104)
  f16* GQ16   = (f16*)(base + 104 * MB);     // 1 MB
  f16* CQ16   = (f16*)(base + 105 * MB);     // 1 MB
  f16* CO16   = (f16*)(base + 106 * MB);     // 1 MB
  f16* WT     = (f16*)(base + 107 * MB);     // 8 MB of transposed f16 weights

  f16* sWqT = WT;
  f16* sWkT = sWqT + 262144;
  f16* sWvT = sWkT + 262144;
  f16* sWoT = sWvT + 262144;
  f16* W1T  = sWoT + 262144;   // [2048][512]
  f16* W2T  = W1T + 1048576;   // [512][2048]
  f16* cWqT = W2T + 1048576;
  f16* cWkT = cWqT + 262144;
  f16* cWvT = cWkT + 262144;
  f16* cWoT = cWvT + 262144;

  WJobs wj;
  {
    const float* wsrc[10] = {sWq, sWk, sWv, sWo, W1, W2, cWq, cWk, cWv, cWo};
    f16* wdst[10] = {sWqT, sWkT, sWvT, sWoT, W1T, W2T, cWqT, cWkT, cWvT, cWoT};
    const int wK[10] = {512,512,512,512, 512,2048, 512,512,512,512};
    const int wN[10] = {512,512,512,512, 2048,512, 512,512,512,512};
    for (int i = 0; i < 10; i++) {
      wj.src[i] = wsrc[i]; wj.dst[i] = wdst[i];
      wj.K[i] = wK[i]; wj.N[i] = wN[i];
      wj.tiles[i] = (wK[i] >> 5) * (wN[i] >> 5);
    }
  }

  const dim3 blk256(256), blk128(128);

  wconv_kernel<<<dim3(1024, 10), blk256, 0, stream>>>(wj);
  embed_kernel<<<N_, blk128, 0, stream>>>(bytes_seq, byte_emb, ngram_emb, E, E16);

  // self-attention QKV projections (f16 out)
  gemm_f16<f16, 0><<<dim3(4, 64), blk256, 0, stream>>>(E16, sWqT, sbq, QH16, N_, 512, 512);
  gemm_f16<f16, 0><<<dim3(4, 64), blk256, 0, stream>>>(E16, sWkT, sbk, KH16, N_, 512, 512);
  gemm_f16<f16, 0><<<dim3(4, 64), blk256, 0, stream>>>(E16, sWvT, sbv, VH16, N_, 512, 512);

  attn_f16<<<dim3(32, 8, 4), blk256, 0, stream>>>(QH16, KH16, VH16, AT16, S_);

  // output projection (f32) + LN1
  gemm_f16<float, 0><<<dim3(4, 64), blk256, 0, stream>>>(AT16, sWoT, sbo, TMP, N_, 512, 512);
  ln_kernel<<<N_, blk128, 0, stream>>>(E, TMP, ln1g, ln1b, X1, X116);

  // FFN
  gemm_f16<f16, 1><<<dim3(16, 64), blk256, 0, stream>>>(X116, W1T, b1, HID16, N_, 2048, 512);
  gemm_f16<float, 0><<<dim3(4, 64), blk256, 0, stream>>>(HID16, W2T, b2, TMP, N_, 512, 2048);
  ln_kernel<<<N_, blk128, 0, stream>>>(X1, TMP, ln2g, ln2b, E /*dead, dummy f32 out*/, X216);

  // cross attention
  gather_f16<<<NP_, blk128, 0, stream>>>(X216, patch_idx, GQ16);
  gemm_f16<f16, 0><<<dim3(4, 8), blk256, 0, stream>>>(GQ16, cWqT, cbq, CQ16, NP_, 512, 512);
  gemm_f16<f16, 0><<<dim3(4, 64), blk256, 0, stream>>>(X216, cWkT, cbk, KH16, N_, 512, 512);
  gemm_f16<f16, 0><<<dim3(4, 64), blk256, 0, stream>>>(X216, cWvT, cbv, VH16, N_, 512, 512);
  attn_f16<<<dim3(4, 8, 4), blk256, 0, stream>>>(CQ16, KH16, VH16, CO16, P_);

  // final projection -> d_out (f32)
  gemm_f16<float, 0><<<dim3(4, 8), blk256, 0, stream>>>(CO16, cWoT, cbo, (float*)d_out, NP_, 512, 512);
}

// Round 4
// 347.000 us; speedup vs baseline: 5.6587x; 1.3338x over previous
//
#include <hip/hip_runtime.h>
#include <stdint.h>

#define B_   4
#define S_   2048
#define D_   512
#define H_   8
#define DH_  64
#define V_   100000
#define P_   256
#define N_   (B_*S_)    // 8192 rows
#define NP_  (B_*P_)    // 1024 rows

typedef _Float16 f16;
typedef _Float16 f16x8 __attribute__((ext_vector_type(8)));
typedef float    f32x4 __attribute__((ext_vector_type(4)));

#define MFMA16(a,b,c) __builtin_amdgcn_mfma_f32_16x16x32_f16((a),(b),(c),0,0,0)
#define GLDS16(gp, lp) __builtin_amdgcn_global_load_lds( \
    (const __attribute__((address_space(1))) void*)(gp), \
    (__attribute__((address_space(3))) void*)(lp), 16, 0, 0)

// ---------------------------------------------------------------------------
// Embedding + n-gram hash -> E (fp32) and E16 (f16)
// masked positions (s < n-1) still ADD ngram row 0.
// ---------------------------------------------------------------------------
__global__ __launch_bounds__(128) void embed_kernel(
    const int* __restrict__ bytes_seq, const float* __restrict__ byte_emb,
    const float* __restrict__ ngram_emb, float* __restrict__ out,
    f16* __restrict__ out16)
{
  const int pos = blockIdx.x;           // 0..N_-1
  const int b = pos / S_, s = pos % S_;
  const int* bs = bytes_seq + (size_t)b * S_;

  int w[8];
  #pragma unroll
  for (int k = 0; k < 8; k++) {
    int p = s - 7 + k;
    w[k] = (p >= 0) ? bs[p] : 0;
  }

  int idx[6];
  #pragma unroll
  for (int j = 0; j < 6; j++) {
    const int n = j + 3;
    int id = 0;
    if (s >= n - 1) {
      uint64_t h = 0;
      for (int k = 0; k < n; k++)
        h += (uint64_t)(uint32_t)w[8 - n + k] << (8 * k);
      long long sh = (long long)h;       // int64 wraparound semantics
      long long r = sh % (long long)V_;  // trunc-mod to floor-mod
      if (r < 0) r += V_;
      id = (int)r;
    }
    idx[j] = id;
  }

  const int d = threadIdx.x * 4;
  float4 acc = *(const float4*)(byte_emb + (size_t)bs[s] * D_ + d);
  #pragma unroll
  for (int j = 0; j < 6; j++) {
    const float4 v = *(const float4*)(ngram_emb + ((size_t)j * V_ + idx[j]) * D_ + d);
    acc.x += v.x; acc.y += v.y; acc.z += v.z; acc.w += v.w;
  }
  const float inv7 = 1.0f / 7.0f;
  acc.x *= inv7; acc.y *= inv7; acc.z *= inv7; acc.w *= inv7;
  *(float4*)(out + (size_t)pos * D_ + d) = acc;
  f16* o16 = out16 + (size_t)pos * D_ + d;
  o16[0] = (f16)acc.x; o16[1] = (f16)acc.y; o16[2] = (f16)acc.z; o16[3] = (f16)acc.w;
}

// ---------------------------------------------------------------------------
// Weight conversion: fp32 [K][N] -> f16 [N][K]  (10 jobs, one launch)
// ---------------------------------------------------------------------------
struct WJobs {
  const float* src[10];
  f16* dst[10];
  int K[10], N[10], tiles[10];
};

__global__ __launch_bounds__(256) void wconv_kernel(WJobs jobs)
{
  const int j = blockIdx.y;
  const int tile = blockIdx.x;
  if (tile >= jobs.tiles[j]) return;
  const int K = jobs.K[j], N = jobs.N[j];
  const int ntiles = N >> 5;
  const int kt = (tile / ntiles) << 5, nt = (tile % ntiles) << 5;
  __shared__ float T[32][33];
  const int t = threadIdx.x;
  const float* src = jobs.src[j];
  #pragma unroll
  for (int p = 0; p < 4; p++) {
    int lin = t + p * 256;
    int rr = lin >> 5, cc = lin & 31;
    T[rr][cc] = src[(size_t)(kt + rr) * N + nt + cc];
  }
  __syncthreads();
  f16* dst = jobs.dst[j];
  #pragma unroll
  for (int p = 0; p < 4; p++) {
    int lin = t + p * 256;
    int rr = lin >> 5, cc = lin & 31;
    dst[(size_t)(nt + rr) * K + kt + cc] = (f16)T[cc][rr];
  }
}

// ---------------------------------------------------------------------------
// Bias concat: bqkv = [sbq|sbk|sbv] (1536), bckv = [cbk|cbv] (1024)
// ---------------------------------------------------------------------------
__global__ __launch_bounds__(256) void bconcat_kernel(
    const float* sbq, const float* sbk, const float* sbv,
    const float* cbk, const float* cbv, float* bqkv, float* bckv)
{
  int t = blockIdx.x * 256 + threadIdx.x;      // grid 10*256 = 2560
  if (t < 512)       bqkv[t] = sbq[t];
  else if (t < 1024) bqkv[t] = sbk[t - 512];
  else if (t < 1536) bqkv[t] = sbv[t - 1024];
  else if (t < 2048) bckv[t - 1536] = cbk[t - 1536];
  else if (t < 2560) bckv[t - 1536] = cbv[t - 2048];
}

// ---------------------------------------------------------------------------
// f16 MFMA GEMM: C[M,N] = A[M,K] @ W[K,N] + bias, W given TRANSPOSED Bt[N][K].
// 128x128 tile, BK=32, 4 waves (2x2), double-buffered global_load_lds.
// grid = (M/128, N/128): blockIdx.x = row-tile so blocks sharing the A panel
// land on the same XCD (gridDim.x multiple of 8).
// rowmap != null: A row r -> (r>>8)*S_ + rowmap[r]  (patch gather fused).
// ---------------------------------------------------------------------------
template<typename OutT, int RELU>
__global__ __launch_bounds__(256) void gemm_f16(
    const f16* __restrict__ A, const f16* __restrict__ Bt,
    const float* __restrict__ bias, OutT* __restrict__ C,
    int M, int N, int K, const int* __restrict__ rowmap)
{
  __shared__ __align__(16) f16 As[2][128 * 32];
  __shared__ __align__(16) f16 Bs[2][128 * 32];
  const int tid = threadIdx.x;
  const int l = tid & 63;
  const int lo4 = l & 15, hi2 = l >> 4;
  const int w = tid >> 6;
  const int wr = w >> 1, wc = w & 1;
  const int bm = blockIdx.x * 128, bn = blockIdx.y * 128;

  // per-thread A row offsets (2 staging rows), with optional indirection
  size_t aoff[2];
  #pragma unroll
  for (int i = 0; i < 2; i++) {
    int r = bm + i * 64 + (tid >> 2);
    int ar = rowmap ? ((r >> 8) * S_ + rowmap[r]) : r;
    aoff[i] = (size_t)ar * K + (tid & 3) * 8;
  }

  f32x4 acc[4][4];
  #pragma unroll
  for (int m = 0; m < 4; m++)
    #pragma unroll
    for (int n = 0; n < 4; n++) acc[m][n] = (f32x4){0.f, 0.f, 0.f, 0.f};

  const int nt = K >> 5;

  #pragma unroll
  for (int i = 0; i < 2; i++) {
    int c = i * 256 + tid;
    GLDS16(A  + aoff[i], &As[0][c * 8]);
    GLDS16(Bt + (size_t)(bn + (c >> 2)) * K + (c & 3) * 8, &Bs[0][c * 8]);
  }

  for (int t = 0; t < nt; t++) {
    __syncthreads();
    const int cur = t & 1;
    if (t + 1 < nt) {
      const int k0 = (t + 1) << 5;
      #pragma unroll
      for (int i = 0; i < 2; i++) {
        int c = i * 256 + tid;
        GLDS16(A  + aoff[i] + k0, &As[cur ^ 1][c * 8]);
        GLDS16(Bt + (size_t)(bn + (c >> 2)) * K + k0 + (c & 3) * 8, &Bs[cur ^ 1][c * 8]);
      }
    }
    f16x8 af[4], bf[4];
    const f16* pa = &As[cur][(wr * 64 + lo4) * 32 + hi2 * 8];
    const f16* pb = &Bs[cur][(wc * 64 + lo4) * 32 + hi2 * 8];
    #pragma unroll
    for (int m = 0; m < 4; m++) af[m] = *(const f16x8*)(pa + m * 16 * 32);
    #pragma unroll
    for (int n = 0; n < 4; n++) bf[n] = *(const f16x8*)(pb + n * 16 * 32);
    #pragma unroll
    for (int m = 0; m < 4; m++)
      #pragma unroll
      for (int n = 0; n < 4; n++)
        acc[m][n] = MFMA16(af[m], bf[n], acc[m][n]);
  }

  #pragma unroll
  for (int n = 0; n < 4; n++) {
    const int col = bn + wc * 64 + n * 16 + lo4;
    const float bcol = bias[col];
    #pragma unroll
    for (int m = 0; m < 4; m++) {
      const int row0 = bm + wr * 64 + m * 16 + hi2 * 4;
      #pragma unroll
      for (int j = 0; j < 4; j++) {
        float v = acc[m][n][j] + bcol;
        if (RELU) v = fmaxf(v, 0.f);
        C[(size_t)(row0 + j) * N + col] = (OutT)v;
      }
    }
  }
}

// ---------------------------------------------------------------------------
// f16 MFMA flash attention, max-free softmax (scores provably small; clamp 15
// in log2 domain as insurance). One barrier per KV tile, double-buffered LDS.
// Q pre-scaled by 0.125*log2(e) so p = exp2(s).
// Grid 1D: lin = (b*8+h) + 32*qt  ->  lin%8 = h (XCD L2 locality for K/V).
// ---------------------------------------------------------------------------
__global__ __launch_bounds__(256) void attn_f16(
    const f16* __restrict__ Q, int qs,
    const f16* __restrict__ Kp, const f16* __restrict__ Vp, int kvs,
    f16* __restrict__ O, int NQ)
{
  __shared__ __align__(16) f16 Ks[2][64][76];
  __shared__ __align__(16) f16 Vt[2][64][76];
  __shared__ __align__(16) f16 Pw[4][16][76];

  const int tid = threadIdx.x;
  const int w = tid >> 6, l = tid & 63;
  const int lo4 = l & 15, hi2 = l >> 4;
  const int lin = blockIdx.x;
  const int h = lin & 7, b = (lin >> 3) & 3, qt = lin >> 5;

  const int qrow = qt * 64 + w * 16 + lo4;
  const f16* Qp = Q + (size_t)(b * NQ + qrow) * qs + h * DH_ + hi2 * 8;
  f16x8 qf[2];
  qf[0] = *(const f16x8*)(Qp);
  qf[1] = *(const f16x8*)(Qp + 32);
  const f16 qscale = (f16)0.18033688f;   // 0.125 * log2(e)
  #pragma unroll
  for (int i = 0; i < 8; i++) { qf[0][i] *= qscale; qf[1][i] *= qscale; }

  const f16* Kb = Kp + (size_t)b * S_ * kvs + h * DH_;
  const f16* Vb = Vp + (size_t)b * S_ * kvs + h * DH_;

  float l_acc[4] = {0.f, 0.f, 0.f, 0.f};
  f32x4 oacc[4];
  #pragma unroll
  for (int df = 0; df < 4; df++) oacc[df] = (f32x4){0.f, 0.f, 0.f, 0.f};

  const int r0 = tid >> 3;   // 0..31
  const int c8 = tid & 7;    // 0..7

  f16x8 kreg[2], vreg[2];
  #pragma unroll
  for (int i = 0; i < 2; i++) {
    int row = i * 32 + r0;
    kreg[i] = *(const f16x8*)(Kb + (size_t)row * kvs + c8 * 8);
    vreg[i] = *(const f16x8*)(Vb + (size_t)row * kvs + c8 * 8);
  }
  #pragma unroll
  for (int i = 0; i < 2; i++) {
    int row = i * 32 + r0;
    *(f16x8*)(&Ks[0][row][c8 * 8]) = kreg[i];
    #pragma unroll
    for (int jj = 0; jj < 8; jj++) Vt[0][c8 * 8 + jj][row] = vreg[i][jj];
  }
  __syncthreads();

  const int NT = S_ / 64;
  int cur = 0;
  for (int t = 0; t < NT; t++) {
    if (t + 1 < NT) {
      #pragma unroll
      for (int i = 0; i < 2; i++) {
        int row = (t + 1) * 64 + i * 32 + r0;
        kreg[i] = *(const f16x8*)(Kb + (size_t)row * kvs + c8 * 8);
        vreg[i] = *(const f16x8*)(Vb + (size_t)row * kvs + c8 * 8);
      }
    }
    // S = (Q*scale) K^T, in log2 domain
    f32x4 sacc[4];
    #pragma unroll
    for (int nf = 0; nf < 4; nf++) {
      f32x4 s = (f32x4){0.f, 0.f, 0.f, 0.f};
      f16x8 kf0 = *(const f16x8*)(&Ks[cur][nf * 16 + lo4][hi2 * 8]);
      f16x8 kf1 = *(const f16x8*)(&Ks[cur][nf * 16 + lo4][32 + hi2 * 8]);
      s = MFMA16(qf[0], kf0, s);
      s = MFMA16(qf[1], kf1, s);
      sacc[nf] = s;
    }
    // p = exp2(s), accumulate row sums per-lane (reduce once at the end)
    #pragma unroll
    for (int nf = 0; nf < 4; nf++)
      #pragma unroll
      for (int j = 0; j < 4; j++) {
        float p = exp2f(fminf(sacc[nf][j], 15.f));
        l_acc[j] += p;
        Pw[w][hi2 * 4 + j][nf * 16 + lo4] = (f16)p;
      }
    // O += P V
    f16x8 pa0 = *(const f16x8*)(&Pw[w][lo4][hi2 * 8]);
    f16x8 pa1 = *(const f16x8*)(&Pw[w][lo4][32 + hi2 * 8]);
    #pragma unroll
    for (int df = 0; df < 4; df++) {
      f16x8 v0 = *(const f16x8*)(&Vt[cur][df * 16 + lo4][hi2 * 8]);
      f16x8 v1 = *(const f16x8*)(&Vt[cur][df * 16 + lo4][32 + hi2 * 8]);
      oacc[df] = MFMA16(pa0, v0, oacc[df]);
      oacc[df] = MFMA16(pa1, v1, oacc[df]);
    }
    // stage next tile into the idle buffer, one barrier per tile
    if (t + 1 < NT) {
      #pragma unroll
      for (int i = 0; i < 2; i++) {
        int row = i * 32 + r0;
        *(f16x8*)(&Ks[cur ^ 1][row][c8 * 8]) = kreg[i];
        #pragma unroll
        for (int jj = 0; jj < 8; jj++) Vt[cur ^ 1][c8 * 8 + jj][row] = vreg[i][jj];
      }
    }
    __syncthreads();
    cur ^= 1;
  }

  // final row-sum reduce across the 16-lane col groups
  #pragma unroll
  for (int j = 0; j < 4; j++) {
    float r = l_acc[j];
    r += __shfl_xor(r, 1, 64);
    r += __shfl_xor(r, 2, 64);
    r += __shfl_xor(r, 4, 64);
    r += __shfl_xor(r, 8, 64);
    l_acc[j] = r;
  }

  #pragma unroll
  for (int df = 0; df < 4; df++) {
    const int col = h * DH_ + df * 16 + lo4;
    #pragma unroll
    for (int j = 0; j < 4; j++) {
      const int row = qt * 64 + w * 16 + hi2 * 4 + j;
      O[(size_t)(b * NQ + row) * D_ + col] = (f16)(oacc[df][j] / l_acc[j]);
    }
  }
}

// ---------------------------------------------------------------------------
// Fused residual + LayerNorm, writes fp32 and f16 copies
// ---------------------------------------------------------------------------
__global__ __launch_bounds__(128) void ln_kernel(
    const float* __restrict__ a, const float* __restrict__ r,
    const float* __restrict__ g, const float* __restrict__ be,
    float* __restrict__ out, f16* __restrict__ out16)
{
  const int row = blockIdx.x;
  const int t = threadIdx.x;
  const float4 va = *(const float4*)(a + (size_t)row * D_ + t * 4);
  const float4 vr = *(const float4*)(r + (size_t)row * D_ + t * 4);
  const float x0 = va.x + vr.x, x1 = va.y + vr.y, x2 = va.z + vr.z, x3 = va.w + vr.w;
  float sm = x0 + x1 + x2 + x3;
  float sq = x0*x0 + x1*x1 + x2*x2 + x3*x3;
  #pragma unroll
  for (int off = 32; off > 0; off >>= 1) {
    sm += __shfl_down(sm, off, 64);
    sq += __shfl_down(sq, off, 64);
  }
  __shared__ float s0[2], s1[2];
  if ((t & 63) == 0) { s0[t >> 6] = sm; s1[t >> 6] = sq; }
  __syncthreads();
  const float Sm = s0[0] + s0[1];
  const float Sq = s1[0] + s1[1];
  const float mean = Sm * (1.0f / 512.0f);
  const float var  = Sq * (1.0f / 512.0f) - mean * mean;
  const float inv  = rsqrtf(var + 1e-5f);
  const float4 vg = *(const float4*)(g + t * 4);
  const float4 vb = *(const float4*)(be + t * 4);
  float4 o;
  o.x = vg.x * (x0 - mean) * inv + vb.x;
  o.y = vg.y * (x1 - mean) * inv + vb.y;
  o.z = vg.z * (x2 - mean) * inv + vb.z;
  o.w = vg.w * (x3 - mean) * inv + vb.w;
  *(float4*)(out + (size_t)row * D_ + t * 4) = o;
  f16* o16 = out16 + (size_t)row * D_ + t * 4;
  o16[0] = (f16)o.x; o16[1] = (f16)o.y; o16[2] = (f16)o.z; o16[3] = (f16)o.w;
}

// ---------------------------------------------------------------------------
extern "C" void kernel_launch(void* const* d_in, const int* in_sizes, int n_in,
                              void* d_out, int out_size, void* d_ws, size_t ws_size,
                              hipStream_t stream) {
  const int*   bytes_seq = (const int*)  d_in[0];
  const int*   patch_idx = (const int*)  d_in[1];
  const float* byte_emb  = (const float*)d_in[2];
  const float* ngram_emb = (const float*)d_in[3];
  const float* sWq = (const float*)d_in[4];  const float* sbq = (const float*)d_in[5];
  const float* sWk = (const float*)d_in[6];  const float* sbk = (const float*)d_in[7];
  const float* sWv = (const float*)d_in[8];  const float* sbv = (const float*)d_in[9];
  const float* sWo = (const float*)d_in[10]; const float* sbo = (const float*)d_in[11];
  const float* ln1g = (const float*)d_in[12]; const float* ln1b = (const float*)d_in[13];
  const float* W1 = (const float*)d_in[14];  const float* b1 = (const float*)d_in[15];
  const float* W2 = (const float*)d_in[16];  const float* b2 = (const float*)d_in[17];
  const float* ln2g = (const float*)d_in[18]; const float* ln2b = (const float*)d_in[19];
  const float* cWq = (const float*)d_in[20]; const float* cbq = (const float*)d_in[21];
  const float* cWk = (const float*)d_in[22]; const float* cbk = (const float*)d_in[23];
  const float* cWv = (const float*)d_in[24]; const float* cbv = (const float*)d_in[25];
  const float* cWo = (const float*)d_in[26]; const float* cbo = (const float*)d_in[27];

  char* base = (char*)d_ws;
  const size_t MB = 1u << 20;
  float* E     = (float*)(base + 0 * MB);     // 16 MB (residual; also LN2 dead f32 out)
  float* TMP   = (float*)(base + 16 * MB);    // 16 MB
  float* X1    = (float*)(base + 32 * MB);    // 16 MB
  f16* E16     = (f16*)(base + 48 * MB);      // 8 MB
  f16* X116    = (f16*)(base + 56 * MB);      // 8 MB
  f16* X216    = (f16*)(base + 64 * MB);      // 8 MB
  f16* QKV16   = (f16*)(base + 72 * MB);      // [8192][1536] = 24 MB
  f16* AT16    = (f16*)(base + 96 * MB);      // 8 MB
  f16* HID16   = (f16*)(base + 104 * MB);     // [8192][2048] = 32 MB
  f16* CKV16   = (f16*)(base + 136 * MB);     // [8192][1024] = 16 MB
  f16* CQ16    = (f16*)(base + 152 * MB);     // 1 MB
  f16* CO16    = (f16*)(base + 153 * MB);     // 1 MB
  f16* WT      = (f16*)(base + 160 * MB);     // 8 MB transposed weights
  float* bqkv  = (float*)(base + 170 * MB);   // 1536 f32
  float* bckv  = bqkv + 1536;                 // 1024 f32

  f16* QKVT = WT;                 // [1536][512]: Wq^T | Wk^T | Wv^T
  f16* sWoT = QKVT + 786432;
  f16* W1T  = sWoT + 262144;      // [2048][512]
  f16* W2T  = W1T + 1048576;      // [512][2048]
  f16* cWqT = W2T + 1048576;
  f16* CKVT = cWqT + 262144;      // [1024][512]: cWk^T | cWv^T
  f16* cWoT = CKVT + 524288;

  WJobs wj;
  {
    const float* wsrc[10] = {sWq, sWk, sWv, sWo, W1, W2, cWq, cWk, cWv, cWo};
    f16* wdst[10] = {QKVT, QKVT + 262144, QKVT + 524288, sWoT, W1T, W2T,
                     cWqT, CKVT, CKVT + 262144, cWoT};
    const int wK[10] = {512,512,512,512, 512,2048, 512,512,512,512};
    const int wN[10] = {512,512,512,512, 2048,512, 512,512,512,512};
    for (int i = 0; i < 10; i++) {
      wj.src[i] = wsrc[i]; wj.dst[i] = wdst[i];
      wj.K[i] = wK[i]; wj.N[i] = wN[i];
      wj.tiles[i] = (wK[i] >> 5) * (wN[i] >> 5);
    }
  }

  const dim3 blk256(256), blk128(128);

  wconv_kernel<<<dim3(1024, 10), blk256, 0, stream>>>(wj);
  bconcat_kernel<<<10, blk256, 0, stream>>>(sbq, sbk, sbv, cbk, cbv, bqkv, bckv);
  embed_kernel<<<N_, blk128, 0, stream>>>(bytes_seq, byte_emb, ngram_emb, E, E16);

  // fused QKV projection: [8192][1536]
  gemm_f16<f16, 0><<<dim3(64, 12), blk256, 0, stream>>>(E16, QKVT, bqkv, QKV16, N_, 1536, 512, nullptr);

  // self-attention (Q,K,V strided views into QKV16)
  attn_f16<<<1024, blk256, 0, stream>>>(QKV16, 1536, QKV16 + 512, QKV16 + 1024, 1536, AT16, S_);

  // output projection (f32) + LN1
  gemm_f16<float, 0><<<dim3(64, 4), blk256, 0, stream>>>(AT16, sWoT, sbo, TMP, N_, 512, 512, nullptr);
  ln_kernel<<<N_, blk128, 0, stream>>>(E, TMP, ln1g, ln1b, X1, X116);

  // FFN
  gemm_f16<f16, 1><<<dim3(64, 16), blk256, 0, stream>>>(X116, W1T, b1, HID16, N_, 2048, 512, nullptr);
  gemm_f16<float, 0><<<dim3(64, 4), blk256, 0, stream>>>(HID16, W2T, b2, TMP, N_, 512, 2048, nullptr);
  ln_kernel<<<N_, blk128, 0, stream>>>(X1, TMP, ln2g, ln2b, E /*dead*/, X216);

  // cross attention: fused K|V projection, gather-fused Q projection
  gemm_f16<f16, 0><<<dim3(64, 8), blk256, 0, stream>>>(X216, CKVT, bckv, CKV16, N_, 1024, 512, nullptr);
  gemm_f16<f16, 0><<<dim3(8, 4), blk256, 0, stream>>>(X216, cWqT, cbq, CQ16, NP_, 512, 512, patch_idx);
  attn_f16<<<128, blk256, 0, stream>>>(CQ16, 512, CKV16, CKV16 + 512, 1024, CO16, P_);

  // final projection -> d_out (f32)
  gemm_f16<float, 0><<<dim3(8, 4), blk256, 0, stream>>>(CO16, cWoT, cbo, (float*)d_out, NP_, 512, 512, nullptr);
}

// Round 6
// 336.108 us; speedup vs baseline: 5.8421x; 1.0324x over previous
//
#include <hip/hip_runtime.h>
#include <stdint.h>

#define B_   4
#define S_   2048
#define D_   512
#define H_   8
#define DH_  64
#define V_   100000
#define P_   256
#define N_   (B_*S_)    // 8192 rows
#define NP_  (B_*P_)    // 1024 rows

typedef _Float16 f16;
typedef _Float16 f16x8 __attribute__((ext_vector_type(8)));
typedef float    f32x4 __attribute__((ext_vector_type(4)));
typedef uint32_t u32x4 __attribute__((ext_vector_type(4)));

#define MFMA16(a,b,c) __builtin_amdgcn_mfma_f32_16x16x32_f16((a),(b),(c),0,0,0)
#define GLDS16(gp, lp) __builtin_amdgcn_global_load_lds( \
    (const __attribute__((address_space(1))) void*)(gp), \
    (__attribute__((address_space(3))) void*)(lp), 16, 0, 0)

// ---------------------------------------------------------------------------
// Embedding + n-gram hash -> E (fp32) and E16 (f16)
// masked positions (s < n-1) still ADD ngram row 0.
// ---------------------------------------------------------------------------
__global__ __launch_bounds__(128) void embed_kernel(
    const int* __restrict__ bytes_seq, const float* __restrict__ byte_emb,
    const float* __restrict__ ngram_emb, float* __restrict__ out,
    f16* __restrict__ out16)
{
  const int pos = blockIdx.x;           // 0..N_-1
  const int b = pos / S_, s = pos % S_;
  const int* bs = bytes_seq + (size_t)b * S_;

  int w[8];
  #pragma unroll
  for (int k = 0; k < 8; k++) {
    int p = s - 7 + k;
    w[k] = (p >= 0) ? bs[p] : 0;
  }

  int idx[6];
  #pragma unroll
  for (int j = 0; j < 6; j++) {
    const int n = j + 3;
    int id = 0;
    if (s >= n - 1) {
      uint64_t h = 0;
      for (int k = 0; k < n; k++)
        h += (uint64_t)(uint32_t)w[8 - n + k] << (8 * k);
      long long sh = (long long)h;       // int64 wraparound semantics
      long long r = sh % (long long)V_;  // trunc-mod to floor-mod
      if (r < 0) r += V_;
      id = (int)r;
    }
    idx[j] = id;
  }

  const int d = threadIdx.x * 4;
  float4 acc = *(const float4*)(byte_emb + (size_t)bs[s] * D_ + d);
  #pragma unroll
  for (int j = 0; j < 6; j++) {
    const float4 v = *(const float4*)(ngram_emb + ((size_t)j * V_ + idx[j]) * D_ + d);
    acc.x += v.x; acc.y += v.y; acc.z += v.z; acc.w += v.w;
  }
  const float inv7 = 1.0f / 7.0f;
  acc.x *= inv7; acc.y *= inv7; acc.z *= inv7; acc.w *= inv7;
  *(float4*)(out + (size_t)pos * D_ + d) = acc;
  f16* o16 = out16 + (size_t)pos * D_ + d;
  o16[0] = (f16)acc.x; o16[1] = (f16)acc.y; o16[2] = (f16)acc.z; o16[3] = (f16)acc.w;
}

// ---------------------------------------------------------------------------
// Weight conversion: fp32 [K][N] -> f16 [N][K]  (10 jobs, one launch)
// ---------------------------------------------------------------------------
struct WJobs {
  const float* src[10];
  f16* dst[10];
  int K[10], N[10], tiles[10];
};

__global__ __launch_bounds__(256) void wconv_kernel(WJobs jobs)
{
  const int j = blockIdx.y;
  const int tile = blockIdx.x;
  if (tile >= jobs.tiles[j]) return;
  const int K = jobs.K[j], N = jobs.N[j];
  const int ntiles = N >> 5;
  const int kt = (tile / ntiles) << 5, nt = (tile % ntiles) << 5;
  __shared__ float T[32][33];
  const int t = threadIdx.x;
  const float* src = jobs.src[j];
  #pragma unroll
  for (int p = 0; p < 4; p++) {
    int lin = t + p * 256;
    int rr = lin >> 5, cc = lin & 31;
    T[rr][cc] = src[(size_t)(kt + rr) * N + nt + cc];
  }
  __syncthreads();
  f16* dst = jobs.dst[j];
  #pragma unroll
  for (int p = 0; p < 4; p++) {
    int lin = t + p * 256;
    int rr = lin >> 5, cc = lin & 31;
    dst[(size_t)(nt + rr) * K + kt + cc] = (f16)T[cc][rr];
  }
}

// ---------------------------------------------------------------------------
// Bias concat: bqkv = [sbq|sbk|sbv] (1536), bckv = [cbk|cbv] (1024)
// ---------------------------------------------------------------------------
__global__ __launch_bounds__(256) void bconcat_kernel(
    const float* sbq, const float* sbk, const float* sbv,
    const float* cbk, const float* cbv, float* bqkv, float* bckv)
{
  int t = blockIdx.x * 256 + threadIdx.x;      // grid 10*256 = 2560
  if (t < 512)       bqkv[t] = sbq[t];
  else if (t < 1024) bqkv[t] = sbk[t - 512];
  else if (t < 1536) bqkv[t] = sbv[t - 1024];
  else if (t < 2048) bckv[t - 1536] = cbk[t - 1536];
  else if (t < 2560) bckv[t - 1536] = cbv[t - 2048];
}

// ---------------------------------------------------------------------------
// f16 MFMA GEMM: C[M,N] = A[M,K] @ W[K,N] + bias, W given TRANSPOSED Bt[N][K].
// 128xBN tile (BN = 128 or 64), BK=32, 4 waves, double-buffered global_load_lds.
// grid = (M/128, N/BN). rowmap: A row r -> (r>>8)*S_ + rowmap[r] (gather fused).
// ---------------------------------------------------------------------------
template<typename OutT, int RELU, int BN>
__global__ __launch_bounds__(256) void gemm_f16(
    const f16* __restrict__ A, const f16* __restrict__ Bt,
    const float* __restrict__ bias, OutT* __restrict__ C,
    int M, int N, int K, const int* __restrict__ rowmap)
{
  constexpr int NF = BN / 32;           // N-frags per wave
  __shared__ __align__(16) f16 As[2][128 * 32];
  __shared__ __align__(16) f16 Bs[2][BN * 32];
  const int tid = threadIdx.x;
  const int l = tid & 63;
  const int lo4 = l & 15, hi2 = l >> 4;
  const int w = tid >> 6;
  const int wr = w >> 1, wc = w & 1;
  const int bm = blockIdx.x * 128, bn = blockIdx.y * BN;

  size_t aoff[2];
  #pragma unroll
  for (int i = 0; i < 2; i++) {
    int r = bm + i * 64 + (tid >> 2);
    int ar = rowmap ? ((r >> 8) * S_ + rowmap[r]) : r;
    aoff[i] = (size_t)ar * K + (tid & 3) * 8;
  }

  f32x4 acc[4][NF];
  #pragma unroll
  for (int m = 0; m < 4; m++)
    #pragma unroll
    for (int n = 0; n < NF; n++) acc[m][n] = (f32x4){0.f, 0.f, 0.f, 0.f};

  const int nt = K >> 5;

  #pragma unroll
  for (int i = 0; i < 2; i++)
    GLDS16(A + aoff[i], &As[0][(i * 256 + tid) * 8]);
  #pragma unroll
  for (int i = 0; i < BN / 64; i++) {
    int c = i * 256 + tid;
    GLDS16(Bt + (size_t)(bn + (c >> 2)) * K + (c & 3) * 8, &Bs[0][c * 8]);
  }

  for (int t = 0; t < nt; t++) {
    __syncthreads();
    const int cur = t & 1;
    if (t + 1 < nt) {
      const int k0 = (t + 1) << 5;
      #pragma unroll
      for (int i = 0; i < 2; i++)
        GLDS16(A + aoff[i] + k0, &As[cur ^ 1][(i * 256 + tid) * 8]);
      #pragma unroll
      for (int i = 0; i < BN / 64; i++) {
        int c = i * 256 + tid;
        GLDS16(Bt + (size_t)(bn + (c >> 2)) * K + k0 + (c & 3) * 8, &Bs[cur ^ 1][c * 8]);
      }
    }
    f16x8 af[4], bf[NF];
    const f16* pa = &As[cur][(wr * 64 + lo4) * 32 + hi2 * 8];
    const f16* pb = &Bs[cur][(wc * (BN / 2) + lo4) * 32 + hi2 * 8];
    #pragma unroll
    for (int m = 0; m < 4; m++) af[m] = *(const f16x8*)(pa + m * 16 * 32);
    #pragma unroll
    for (int n = 0; n < NF; n++) bf[n] = *(const f16x8*)(pb + n * 16 * 32);
    #pragma unroll
    for (int m = 0; m < 4; m++)
      #pragma unroll
      for (int n = 0; n < NF; n++)
        acc[m][n] = MFMA16(af[m], bf[n], acc[m][n]);
  }

  #pragma unroll
  for (int n = 0; n < NF; n++) {
    const int col = bn + wc * (BN / 2) + n * 16 + lo4;
    const float bcol = bias[col];
    #pragma unroll
    for (int m = 0; m < 4; m++) {
      const int row0 = bm + wr * 64 + m * 16 + hi2 * 4;
      #pragma unroll
      for (int j = 0; j < 4; j++) {
        float v = acc[m][n][j] + bcol;
        if (RELU) v = fmaxf(v, 0.f);
        C[(size_t)(row0 + j) * N + col] = (OutT)v;
      }
    }
  }
}

// ---------------------------------------------------------------------------
// f16 MFMA flash attention, max-free softmax (p = exp2(s), clamp 15), swapped
// QK^T with permuted K-rows so P stays in registers: PV B-operand assembled
// via cvt_pkrtz + ds_bpermute (lane <-> lane^32). One barrier per KV tile.
//
// Per-nf K-row permutation: nf0: kv=8*g+j, nf1: kv=8*(g^2)+4+j (+32 for nf2/3)
// where g=(lane&15)>>2, j=lane&3. Then lane group hi2 holds exactly
// P^T[kv = ks*32+8*hi2+i][q = lane&15] for PV after swapping packs with
// lane^32. O computed as O^T = V^T P^T: lane holds O[q=lo4][d=df*16+hi2*4+j].
// ---------------------------------------------------------------------------
__global__ __launch_bounds__(256) void attn_f16(
    const f16* __restrict__ Q, int qs,
    const f16* __restrict__ Kp, const f16* __restrict__ Vp, int kvs,
    f16* __restrict__ O, int NQ)
{
  __shared__ __align__(16) f16 Ks[2][64][76];
  __shared__ __align__(16) f16 Vt[2][64][76];

  const int tid = threadIdx.x;
  const int w = tid >> 6, l = tid & 63;
  const int lo4 = l & 15, hi2 = l >> 4;
  const int lin = blockIdx.x;
  const int h = lin & 7, b = (lin >> 3) & 3, qt = lin >> 5;

  // Q fragment (B-operand: col=q=lane&15, k = hi2*8+i), pre-scaled to log2 dom
  const int qrow = qt * 64 + w * 16 + lo4;
  const f16* Qp = Q + (size_t)(b * NQ + qrow) * qs + h * DH_ + hi2 * 8;
  f16x8 qf[2];
  qf[0] = *(const f16x8*)(Qp);
  qf[1] = *(const f16x8*)(Qp + 32);
  const f16 qscale = (f16)0.18033688f;   // 0.125 * log2(e)
  #pragma unroll
  for (int i = 0; i < 8; i++) { qf[0][i] *= qscale; qf[1][i] *= qscale; }

  // permuted K-row indices for the QK^T A-fragment
  const int g2 = lo4 >> 2, j4 = lo4 & 3;
  const int kvp0 = 8 * g2 + j4;              // nf=0 (own block)
  const int kvp1 = 8 * (g2 ^ 2) + 4 + j4;    // nf=1 (partner block)
  const int pidx = (l ^ 32) << 2;            // bpermute partner index

  const f16* Kb = Kp + (size_t)b * S_ * kvs + h * DH_;
  const f16* Vb = Vp + (size_t)b * S_ * kvs + h * DH_;

  float lsum = 0.f;
  f32x4 oacc[4];
  #pragma unroll
  for (int df = 0; df < 4; df++) oacc[df] = (f32x4){0.f, 0.f, 0.f, 0.f};

  const int r0 = tid >> 3;   // staging row 0..31
  const int c8 = tid & 7;    // 8-elem col chunk

  f16x8 kreg[2], vreg[2];
  #pragma unroll
  for (int i = 0; i < 2; i++) {
    int row = i * 32 + r0;
    kreg[i] = *(const f16x8*)(Kb + (size_t)row * kvs + c8 * 8);
    vreg[i] = *(const f16x8*)(Vb + (size_t)row * kvs + c8 * 8);
  }
  #pragma unroll
  for (int i = 0; i < 2; i++) {
    int row = i * 32 + r0;
    *(f16x8*)(&Ks[0][row][c8 * 8]) = kreg[i];
    #pragma unroll
    for (int jj = 0; jj < 8; jj++) Vt[0][c8 * 8 + jj][row] = vreg[i][jj];
  }
  __syncthreads();

  const int NT = S_ / 64;
  int cur = 0;
  for (int t = 0; t < NT; t++) {
    if (t + 1 < NT) {
      #pragma unroll
      for (int i = 0; i < 2; i++) {
        int row = (t + 1) * 64 + i * 32 + r0;
        kreg[i] = *(const f16x8*)(Kb + (size_t)row * kvs + c8 * 8);
        vreg[i] = *(const f16x8*)(Vb + (size_t)row * kvs + c8 * 8);
      }
    }
    // S^T = K Q^T in log2 domain; sacc[nf][j] = S[kvperm(nf,hi2*4+j)][q=lo4]
    f32x4 sacc[4];
    #pragma unroll
    for (int nf = 0; nf < 4; nf++) {
      const int krow = ((nf & 1) ? kvp1 : kvp0) + (nf >> 1) * 32;
      f32x4 s = (f32x4){0.f, 0.f, 0.f, 0.f};
      f16x8 kf0 = *(const f16x8*)(&Ks[cur][krow][hi2 * 8]);
      f16x8 kf1 = *(const f16x8*)(&Ks[cur][krow][32 + hi2 * 8]);
      s = MFMA16(kf0, qf[0], s);
      s = MFMA16(kf1, qf[1], s);
      sacc[nf] = s;
    }
    // p = exp2(s); per-lane partial row-sum; pack to f16 pairs
    uint32_t packs[4][2];
    #pragma unroll
    for (int nf = 0; nf < 4; nf++) {
      float p0 = exp2f(fminf(sacc[nf][0], 15.f));
      float p1 = exp2f(fminf(sacc[nf][1], 15.f));
      float p2 = exp2f(fminf(sacc[nf][2], 15.f));
      float p3 = exp2f(fminf(sacc[nf][3], 15.f));
      lsum += (p0 + p1) + (p2 + p3);
      packs[nf][0] = __builtin_bit_cast(uint32_t, __builtin_amdgcn_cvt_pkrtz(p0, p1));
      packs[nf][1] = __builtin_bit_cast(uint32_t, __builtin_amdgcn_cvt_pkrtz(p2, p3));
    }
    // O^T += V^T P^T: assemble B-operand (P^T) per 32-kv chunk
    #pragma unroll
    for (int ks = 0; ks < 2; ks++) {
      uint32_t w0 = packs[2 * ks][0];
      uint32_t w1 = packs[2 * ks][1];
      uint32_t w2 = (uint32_t)__builtin_amdgcn_ds_bpermute(pidx, (int)packs[2 * ks + 1][0]);
      uint32_t w3 = (uint32_t)__builtin_amdgcn_ds_bpermute(pidx, (int)packs[2 * ks + 1][1]);
      u32x4 bw = (u32x4){w0, w1, w2, w3};
      f16x8 pb = __builtin_bit_cast(f16x8, bw);
      #pragma unroll
      for (int df = 0; df < 4; df++) {
        f16x8 vf = *(const f16x8*)(&Vt[cur][df * 16 + lo4][ks * 32 + hi2 * 8]);
        oacc[df] = MFMA16(vf, pb, oacc[df]);
      }
    }
    // stage next tile into idle buffer, one barrier per tile
    if (t + 1 < NT) {
      #pragma unroll
      for (int i = 0; i < 2; i++) {
        int row = i * 32 + r0;
        *(f16x8*)(&Ks[cur ^ 1][row][c8 * 8]) = kreg[i];
        #pragma unroll
        for (int jj = 0; jj < 8; jj++) Vt[cur ^ 1][c8 * 8 + jj][row] = vreg[i][jj];
      }
    }
    __syncthreads();
    cur ^= 1;
  }

  // row-sum: reduce over the 4 lane groups holding the same q
  lsum += __shfl_xor(lsum, 16, 64);
  lsum += __shfl_xor(lsum, 32, 64);
  const float invl = 1.0f / lsum;

  // write O: lane holds q=lo4, d = df*16 + hi2*4 + j (4 consecutive cols)
  const int orow = qt * 64 + w * 16 + lo4;
  f16* Ob = O + (size_t)(b * NQ + orow) * D_ + h * DH_ + hi2 * 4;
  #pragma unroll
  for (int df = 0; df < 4; df++) {
    f16 t4[4];
    #pragma unroll
    for (int j = 0; j < 4; j++) t4[j] = (f16)(oacc[df][j] * invl);
    *(uint2*)(Ob + df * 16) = *(uint2*)t4;
  }
}

// ---------------------------------------------------------------------------
// Fused residual + LayerNorm, writes fp32 and f16 copies
// ---------------------------------------------------------------------------
__global__ __launch_bounds__(128) void ln_kernel(
    const float* __restrict__ a, const float* __restrict__ r,
    const float* __restrict__ g, const float* __restrict__ be,
    float* __restrict__ out, f16* __restrict__ out16)
{
  const int row = blockIdx.x;
  const int t = threadIdx.x;
  const float4 va = *(const float4*)(a + (size_t)row * D_ + t * 4);
  const float4 vr = *(const float4*)(r + (size_t)row * D_ + t * 4);
  const float x0 = va.x + vr.x, x1 = va.y + vr.y, x2 = va.z + vr.z, x3 = va.w + vr.w;
  float sm = x0 + x1 + x2 + x3;
  float sq = x0*x0 + x1*x1 + x2*x2 + x3*x3;
  #pragma unroll
  for (int off = 32; off > 0; off >>= 1) {
    sm += __shfl_down(sm, off, 64);
    sq += __shfl_down(sq, off, 64);
  }
  __shared__ float s0[2], s1[2];
  if ((t & 63) == 0) { s0[t >> 6] = sm; s1[t >> 6] = sq; }
  __syncthreads();
  const float Sm = s0[0] + s0[1];
  const float Sq = s1[0] + s1[1];
  const float mean = Sm * (1.0f / 512.0f);
  const float var  = Sq * (1.0f / 512.0f) - mean * mean;
  const float inv  = rsqrtf(var + 1e-5f);
  const float4 vg = *(const float4*)(g + t * 4);
  const float4 vb = *(const float4*)(be + t * 4);
  float4 o;
  o.x = vg.x * (x0 - mean) * inv + vb.x;
  o.y = vg.y * (x1 - mean) * inv + vb.y;
  o.z = vg.z * (x2 - mean) * inv + vb.z;
  o.w = vg.w * (x3 - mean) * inv + vb.w;
  *(float4*)(out + (size_t)row * D_ + t * 4) = o;
  f16* o16 = out16 + (size_t)row * D_ + t * 4;
  o16[0] = (f16)o.x; o16[1] = (f16)o.y; o16[2] = (f16)o.z; o16[3] = (f16)o.w;
}

// ---------------------------------------------------------------------------
extern "C" void kernel_launch(void* const* d_in, const int* in_sizes, int n_in,
                              void* d_out, int out_size, void* d_ws, size_t ws_size,
                              hipStream_t stream) {
  const int*   bytes_seq = (const int*)  d_in[0];
  const int*   patch_idx = (const int*)  d_in[1];
  const float* byte_emb  = (const float*)d_in[2];
  const float* ngram_emb = (const float*)d_in[3];
  const float* sWq = (const float*)d_in[4];  const float* sbq = (const float*)d_in[5];
  const float* sWk = (const float*)d_in[6];  const float* sbk = (const float*)d_in[7];
  const float* sWv = (const float*)d_in[8];  const float* sbv = (const float*)d_in[9];
  const float* sWo = (const float*)d_in[10]; const float* sbo = (const float*)d_in[11];
  const float* ln1g = (const float*)d_in[12]; const float* ln1b = (const float*)d_in[13];
  const float* W1 = (const float*)d_in[14];  const float* b1 = (const float*)d_in[15];
  const float* W2 = (const float*)d_in[16];  const float* b2 = (const float*)d_in[17];
  const float* ln2g = (const float*)d_in[18]; const float* ln2b = (const float*)d_in[19];
  const float* cWq = (const float*)d_in[20]; const float* cbq = (const float*)d_in[21];
  const float* cWk = (const float*)d_in[22]; const float* cbk = (const float*)d_in[23];
  const float* cWv = (const float*)d_in[24]; const float* cbv = (const float*)d_in[25];
  const float* cWo = (const float*)d_in[26]; const float* cbo = (const float*)d_in[27];

  char* base = (char*)d_ws;
  const size_t MB = 1u << 20;
  float* E     = (float*)(base + 0 * MB);     // 16 MB (residual; LN2 dead f32 out)
  float* TMP   = (float*)(base + 16 * MB);    // 16 MB
  float* X1    = (float*)(base + 32 * MB);    // 16 MB
  f16* E16     = (f16*)(base + 48 * MB);      // 8 MB
  f16* X116    = (f16*)(base + 56 * MB);      // 8 MB
  f16* X216    = (f16*)(base + 64 * MB);      // 8 MB
  f16* QKV16   = (f16*)(base + 72 * MB);      // [8192][1536] = 24 MB
  f16* AT16    = (f16*)(base + 96 * MB);      // 8 MB
  f16* HID16   = (f16*)(base + 104 * MB);     // [8192][2048] = 32 MB
  f16* CKV16   = (f16*)(base + 136 * MB);     // [8192][1024] = 16 MB
  f16* CQ16    = (f16*)(base + 152 * MB);     // 1 MB
  f16* CO16    = (f16*)(base + 153 * MB);     // 1 MB
  f16* WT      = (f16*)(base + 160 * MB);     // 8 MB transposed weights
  float* bqkv  = (float*)(base + 170 * MB);   // 1536 f32
  float* bckv  = bqkv + 1536;                 // 1024 f32

  f16* QKVT = WT;                 // [1536][512]: Wq^T | Wk^T | Wv^T
  f16* sWoT = QKVT + 786432;
  f16* W1T  = sWoT + 262144;      // [2048][512]
  f16* W2T  = W1T + 1048576;      // [512][2048]
  f16* cWqT = W2T + 1048576;
  f16* CKVT = cWqT + 262144;      // [1024][512]: cWk^T | cWv^T
  f16* cWoT = CKVT + 524288;

  WJobs wj;
  {
    const float* wsrc[10] = {sWq, sWk, sWv, sWo, W1, W2, cWq, cWk, cWv, cWo};
    f16* wdst[10] = {QKVT, QKVT + 262144, QKVT + 524288, sWoT, W1T, W2T,
                     cWqT, CKVT, CKVT + 262144, cWoT};
    const int wK[10] = {512,512,512,512, 512,2048, 512,512,512,512};
    const int wN[10] = {512,512,512,512, 2048,512, 512,512,512,512};
    for (int i = 0; i < 10; i++) {
      wj.src[i] = wsrc[i]; wj.dst[i] = wdst[i];
      wj.K[i] = wK[i]; wj.N[i] = wN[i];
      wj.tiles[i] = (wK[i] >> 5) * (wN[i] >> 5);
    }
  }

  const dim3 blk256(256), blk128(128);

  wconv_kernel<<<dim3(1024, 10), blk256, 0, stream>>>(wj);
  bconcat_kernel<<<10, blk256, 0, stream>>>(sbq, sbk, sbv, cbk, cbv, bqkv, bckv);
  embed_kernel<<<N_, blk128, 0, stream>>>(bytes_seq, byte_emb, ngram_emb, E, E16);

  // fused QKV projection: [8192][1536]
  gemm_f16<f16, 0, 128><<<dim3(64, 12), blk256, 0, stream>>>(E16, QKVT, bqkv, QKV16, N_, 1536, 512, nullptr);

  // self-attention (Q,K,V strided views into QKV16)
  attn_f16<<<1024, blk256, 0, stream>>>(QKV16, 1536, QKV16 + 512, QKV16 + 1024, 1536, AT16, S_);

  // output projection (f32) + LN1
  gemm_f16<float, 0, 64><<<dim3(64, 8), blk256, 0, stream>>>(AT16, sWoT, sbo, TMP, N_, 512, 512, nullptr);
  ln_kernel<<<N_, blk128, 0, stream>>>(E, TMP, ln1g, ln1b, X1, X116);

  // FFN
  gemm_f16<f16, 1, 128><<<dim3(64, 16), blk256, 0, stream>>>(X116, W1T, b1, HID16, N_, 2048, 512, nullptr);
  gemm_f16<float, 0, 64><<<dim3(64, 8), blk256, 0, stream>>>(HID16, W2T, b2, TMP, N_, 512, 2048, nullptr);
  ln_kernel<<<N_, blk128, 0, stream>>>(X1, TMP, ln2g, ln2b, E /*dead*/, X216);

  // cross attention: fused K|V projection, gather-fused Q projection
  gemm_f16<f16, 0, 128><<<dim3(64, 8), blk256, 0, stream>>>(X216, CKVT, bckv, CKV16, N_, 1024, 512, nullptr);
  gemm_f16<f16, 0, 64><<<dim3(8, 8), blk256, 0, stream>>>(X216, cWqT, cbq, CQ16, NP_, 512, 512, patch_idx);
  attn_f16<<<128, blk256, 0, stream>>>(CQ16, 512, CKV16, CKV16 + 512, 1024, CO16, P_);

  // final projection -> d_out (f32)
  gemm_f16<float, 0, 64><<<dim3(8, 8), blk256, 0, stream>>>(CO16, cWoT, cbo, (float*)d_out, NP_, 512, 512, nullptr);
}

// Round 7
// 287.447 us; speedup vs baseline: 6.8311x; 1.1693x over previous
//
#include <hip/hip_runtime.h>
#include <stdint.h>

#define B_   4
#define S_   2048
#define D_   512
#define H_   8
#define DH_  64
#define V_   100000
#define P_   256
#define N_   (B_*S_)    // 8192 rows
#define NP_  (B_*P_)    // 1024 rows

typedef _Float16 f16;
typedef _Float16 f16x8 __attribute__((ext_vector_type(8)));
typedef float    f32x4 __attribute__((ext_vector_type(4)));
typedef uint32_t u32x4 __attribute__((ext_vector_type(4)));

#define MFMA16(a,b,c) __builtin_amdgcn_mfma_f32_16x16x32_f16((a),(b),(c),0,0,0)
#define GLDS16(gp, lp) __builtin_amdgcn_global_load_lds( \
    (const __attribute__((address_space(1))) void*)(gp), \
    (__attribute__((address_space(3))) void*)(lp), 16, 0, 0)

// ---------------------------------------------------------------------------
// Embedding + n-gram hash -> E16 (f16 only; residual path is f16)
// masked positions (s < n-1) still ADD ngram row 0.
// ---------------------------------------------------------------------------
__global__ __launch_bounds__(128) void embed_kernel(
    const int* __restrict__ bytes_seq, const float* __restrict__ byte_emb,
    const float* __restrict__ ngram_emb, f16* __restrict__ out16)
{
  const int pos = blockIdx.x;           // 0..N_-1
  const int b = pos / S_, s = pos % S_;
  const int* bs = bytes_seq + (size_t)b * S_;

  int w[8];
  #pragma unroll
  for (int k = 0; k < 8; k++) {
    int p = s - 7 + k;
    w[k] = (p >= 0) ? bs[p] : 0;
  }

  int idx[6];
  #pragma unroll
  for (int j = 0; j < 6; j++) {
    const int n = j + 3;
    int id = 0;
    if (s >= n - 1) {
      uint64_t h = 0;
      for (int k = 0; k < n; k++)
        h += (uint64_t)(uint32_t)w[8 - n + k] << (8 * k);
      long long sh = (long long)h;       // int64 wraparound semantics
      long long r = sh % (long long)V_;  // trunc-mod to floor-mod
      if (r < 0) r += V_;
      id = (int)r;
    }
    idx[j] = id;
  }

  const int d = threadIdx.x * 4;
  float4 acc = *(const float4*)(byte_emb + (size_t)bs[s] * D_ + d);
  #pragma unroll
  for (int j = 0; j < 6; j++) {
    const float4 v = *(const float4*)(ngram_emb + ((size_t)j * V_ + idx[j]) * D_ + d);
    acc.x += v.x; acc.y += v.y; acc.z += v.z; acc.w += v.w;
  }
  const float inv7 = 1.0f / 7.0f;
  f16* o16 = out16 + (size_t)pos * D_ + d;
  f16 t4[4];
  t4[0] = (f16)(acc.x * inv7); t4[1] = (f16)(acc.y * inv7);
  t4[2] = (f16)(acc.z * inv7); t4[3] = (f16)(acc.w * inv7);
  *(uint2*)o16 = *(uint2*)t4;
}

// ---------------------------------------------------------------------------
// Weight conversion fp32 [K][N] -> f16 [N][K] (10 jobs) + fused bias concat.
// ---------------------------------------------------------------------------
struct WJobs {
  const float* src[10];
  f16* dst[10];
  int K[10], N[10], tiles[10];
};

__global__ __launch_bounds__(256) void wconv_kernel(WJobs jobs,
    const float* sbq, const float* sbk, const float* sbv,
    const float* cbk, const float* cbv, float* bqkv, float* bckv)
{
  const int j = blockIdx.y;
  const int tile = blockIdx.x;
  if (j == 0 && tile >= jobs.tiles[0] && tile < jobs.tiles[0] + 10) {
    int t = (tile - jobs.tiles[0]) * 256 + threadIdx.x;   // 0..2559
    if (t < 512)       bqkv[t] = sbq[t];
    else if (t < 1024) bqkv[t] = sbk[t - 512];
    else if (t < 1536) bqkv[t] = sbv[t - 1024];
    else if (t < 2048) bckv[t - 1536] = cbk[t - 1536];
    else if (t < 2560) bckv[t - 1536] = cbv[t - 2048];
    return;
  }
  if (tile >= jobs.tiles[j]) return;
  const int K = jobs.K[j], N = jobs.N[j];
  const int ntiles = N >> 5;
  const int kt = (tile / ntiles) << 5, nt = (tile % ntiles) << 5;
  __shared__ float T[32][33];
  const int t = threadIdx.x;
  const float* src = jobs.src[j];
  #pragma unroll
  for (int p = 0; p < 4; p++) {
    int lin = t + p * 256;
    int rr = lin >> 5, cc = lin & 31;
    T[rr][cc] = src[(size_t)(kt + rr) * N + nt + cc];
  }
  __syncthreads();
  f16* dst = jobs.dst[j];
  #pragma unroll
  for (int p = 0; p < 4; p++) {
    int lin = t + p * 256;
    int rr = lin >> 5, cc = lin & 31;
    dst[(size_t)(nt + rr) * K + kt + cc] = (f16)T[cc][rr];
  }
}

// ---------------------------------------------------------------------------
// f16 MFMA GEMM: C[M,N] = A[M,K] @ W[K,N] + bias, W given TRANSPOSED Bt[N][K].
// 128xBN tile (BN = 128 or 64), BK=32, 4 waves, double-buffered global_load_lds.
// rowmap: A row r -> (r>>8)*S_ + rowmap[r] (patch gather fused).
// ---------------------------------------------------------------------------
template<typename OutT, int RELU, int BN>
__global__ __launch_bounds__(256) void gemm_f16(
    const f16* __restrict__ A, const f16* __restrict__ Bt,
    const float* __restrict__ bias, OutT* __restrict__ C,
    int M, int N, int K, const int* __restrict__ rowmap)
{
  constexpr int NF = BN / 32;           // N-frags per wave
  __shared__ __align__(16) f16 As[2][128 * 32];
  __shared__ __align__(16) f16 Bs[2][BN * 32];
  const int tid = threadIdx.x;
  const int l = tid & 63;
  const int lo4 = l & 15, hi2 = l >> 4;
  const int w = tid >> 6;
  const int wr = w >> 1, wc = w & 1;
  const int bm = blockIdx.x * 128, bn = blockIdx.y * BN;

  size_t aoff[2];
  #pragma unroll
  for (int i = 0; i < 2; i++) {
    int r = bm + i * 64 + (tid >> 2);
    int ar = rowmap ? ((r >> 8) * S_ + rowmap[r]) : r;
    aoff[i] = (size_t)ar * K + (tid & 3) * 8;
  }

  f32x4 acc[4][NF];
  #pragma unroll
  for (int m = 0; m < 4; m++)
    #pragma unroll
    for (int n = 0; n < NF; n++) acc[m][n] = (f32x4){0.f, 0.f, 0.f, 0.f};

  const int nt = K >> 5;

  #pragma unroll
  for (int i = 0; i < 2; i++)
    GLDS16(A + aoff[i], &As[0][(i * 256 + tid) * 8]);
  #pragma unroll
  for (int i = 0; i < BN / 64; i++) {
    int c = i * 256 + tid;
    GLDS16(Bt + (size_t)(bn + (c >> 2)) * K + (c & 3) * 8, &Bs[0][c * 8]);
  }

  for (int t = 0; t < nt; t++) {
    __syncthreads();
    const int cur = t & 1;
    if (t + 1 < nt) {
      const int k0 = (t + 1) << 5;
      #pragma unroll
      for (int i = 0; i < 2; i++)
        GLDS16(A + aoff[i] + k0, &As[cur ^ 1][(i * 256 + tid) * 8]);
      #pragma unroll
      for (int i = 0; i < BN / 64; i++) {
        int c = i * 256 + tid;
        GLDS16(Bt + (size_t)(bn + (c >> 2)) * K + k0 + (c & 3) * 8, &Bs[cur ^ 1][c * 8]);
      }
    }
    f16x8 af[4], bf[NF];
    const f16* pa = &As[cur][(wr * 64 + lo4) * 32 + hi2 * 8];
    const f16* pb = &Bs[cur][(wc * (BN / 2) + lo4) * 32 + hi2 * 8];
    #pragma unroll
    for (int m = 0; m < 4; m++) af[m] = *(const f16x8*)(pa + m * 16 * 32);
    #pragma unroll
    for (int n = 0; n < NF; n++) bf[n] = *(const f16x8*)(pb + n * 16 * 32);
    #pragma unroll
    for (int m = 0; m < 4; m++)
      #pragma unroll
      for (int n = 0; n < NF; n++)
        acc[m][n] = MFMA16(af[m], bf[n], acc[m][n]);
  }

  #pragma unroll
  for (int n = 0; n < NF; n++) {
    const int col = bn + wc * (BN / 2) + n * 16 + lo4;
    const float bcol = bias[col];
    #pragma unroll
    for (int m = 0; m < 4; m++) {
      const int row0 = bm + wr * 64 + m * 16 + hi2 * 4;
      #pragma unroll
      for (int j = 0; j < 4; j++) {
        float v = acc[m][n][j] + bcol;
        if (RELU) v = fmaxf(v, 0.f);
        C[(size_t)(row0 + j) * N + col] = (OutT)v;
      }
    }
  }
}

// ---------------------------------------------------------------------------
// f16 MFMA flash attention, max-free softmax (p = exp2(s), clamp 15), swapped
// QK^T with permuted K-rows; P in registers via cvt_pkrtz + ds_bpermute.
// QG q-groups of 16 rows per wave (QG=2: 32 q/wave, 128 q/block) — K/V
// fragments are read from LDS ONCE and reused across q-groups.
// Grid 1D: lin = (b*8+h) + 32*qt  (lin%8 = h for XCD L2 locality).
// ---------------------------------------------------------------------------
template<int QG>
__global__ __launch_bounds__(256) void attn_f16(
    const f16* __restrict__ Q, int qs,
    const f16* __restrict__ Kp, const f16* __restrict__ Vp, int kvs,
    f16* __restrict__ O, int NQ)
{
  __shared__ __align__(16) f16 Ks[2][64][76];
  __shared__ __align__(16) f16 Vt[2][64][76];

  const int tid = threadIdx.x;
  const int w = tid >> 6, l = tid & 63;
  const int lo4 = l & 15, hi2 = l >> 4;
  const int lin = blockIdx.x;
  const int h = lin & 7, b = (lin >> 3) & 3, qt = lin >> 5;

  // Q fragments (B-operand: col=q=lane&15, k = hi2*8+i), pre-scaled (log2 dom)
  const f16 qscale = (f16)0.18033688f;   // 0.125 * log2(e)
  f16x8 qf[QG][2];
  #pragma unroll
  for (int qg = 0; qg < QG; qg++) {
    const int qrow = qt * (64 * QG) + w * (16 * QG) + qg * 16 + lo4;
    const f16* Qp = Q + (size_t)(b * NQ + qrow) * qs + h * DH_ + hi2 * 8;
    qf[qg][0] = *(const f16x8*)(Qp);
    qf[qg][1] = *(const f16x8*)(Qp + 32);
    #pragma unroll
    for (int i = 0; i < 8; i++) { qf[qg][0][i] *= qscale; qf[qg][1][i] *= qscale; }
  }

  // permuted K-row indices for the QK^T A-fragment
  const int g2 = lo4 >> 2, j4 = lo4 & 3;
  const int kvp0 = 8 * g2 + j4;              // nf=0 (own block)
  const int kvp1 = 8 * (g2 ^ 2) + 4 + j4;    // nf=1 (partner block)
  const int pidx = (l ^ 32) << 2;            // bpermute partner index

  const f16* Kb = Kp + (size_t)b * S_ * kvs + h * DH_;
  const f16* Vb = Vp + (size_t)b * S_ * kvs + h * DH_;

  float lsum[QG];
  f32x4 oacc[QG][4];
  #pragma unroll
  for (int qg = 0; qg < QG; qg++) {
    lsum[qg] = 0.f;
    #pragma unroll
    for (int df = 0; df < 4; df++) oacc[qg][df] = (f32x4){0.f, 0.f, 0.f, 0.f};
  }

  const int r0 = tid >> 3;   // staging row 0..31
  const int c8 = tid & 7;    // 8-elem col chunk

  f16x8 kreg[2], vreg[2];
  #pragma unroll
  for (int i = 0; i < 2; i++) {
    int row = i * 32 + r0;
    kreg[i] = *(const f16x8*)(Kb + (size_t)row * kvs + c8 * 8);
    vreg[i] = *(const f16x8*)(Vb + (size_t)row * kvs + c8 * 8);
  }
  #pragma unroll
  for (int i = 0; i < 2; i++) {
    int row = i * 32 + r0;
    *(f16x8*)(&Ks[0][row][c8 * 8]) = kreg[i];
    #pragma unroll
    for (int jj = 0; jj < 8; jj++) Vt[0][c8 * 8 + jj][row] = vreg[i][jj];
  }
  __syncthreads();

  const int NT = S_ / 64;
  int cur = 0;
  for (int t = 0; t < NT; t++) {
    if (t + 1 < NT) {
      #pragma unroll
      for (int i = 0; i < 2; i++) {
        int row = (t + 1) * 64 + i * 32 + r0;
        kreg[i] = *(const f16x8*)(Kb + (size_t)row * kvs + c8 * 8);
        vreg[i] = *(const f16x8*)(Vb + (size_t)row * kvs + c8 * 8);
      }
    }
    // S^T = K Q^T (log2 domain); K-fragments shared across q-groups
    f32x4 sacc[QG][4];
    #pragma unroll
    for (int nf = 0; nf < 4; nf++) {
      const int krow = ((nf & 1) ? kvp1 : kvp0) + (nf >> 1) * 32;
      f16x8 kf0 = *(const f16x8*)(&Ks[cur][krow][hi2 * 8]);
      f16x8 kf1 = *(const f16x8*)(&Ks[cur][krow][32 + hi2 * 8]);
      #pragma unroll
      for (int qg = 0; qg < QG; qg++) {
        f32x4 s = (f32x4){0.f, 0.f, 0.f, 0.f};
        s = MFMA16(kf0, qf[qg][0], s);
        s = MFMA16(kf1, qf[qg][1], s);
        sacc[qg][nf] = s;
      }
    }
    // p = exp2(s); per-lane partial row-sum; pack to f16 pairs
    uint32_t packs[QG][4][2];
    #pragma unroll
    for (int qg = 0; qg < QG; qg++)
      #pragma unroll
      for (int nf = 0; nf < 4; nf++) {
        float p0 = exp2f(fminf(sacc[qg][nf][0], 15.f));
        float p1 = exp2f(fminf(sacc[qg][nf][1], 15.f));
        float p2 = exp2f(fminf(sacc[qg][nf][2], 15.f));
        float p3 = exp2f(fminf(sacc[qg][nf][3], 15.f));
        lsum[qg] += (p0 + p1) + (p2 + p3);
        packs[qg][nf][0] = __builtin_bit_cast(uint32_t, __builtin_amdgcn_cvt_pkrtz(p0, p1));
        packs[qg][nf][1] = __builtin_bit_cast(uint32_t, __builtin_amdgcn_cvt_pkrtz(p2, p3));
      }
    // O^T += V^T P^T: V-fragments shared across q-groups
    #pragma unroll
    for (int ks = 0; ks < 2; ks++) {
      f16x8 pb[QG];
      #pragma unroll
      for (int qg = 0; qg < QG; qg++) {
        uint32_t w0 = packs[qg][2 * ks][0];
        uint32_t w1 = packs[qg][2 * ks][1];
        uint32_t w2 = (uint32_t)__builtin_amdgcn_ds_bpermute(pidx, (int)packs[qg][2 * ks + 1][0]);
        uint32_t w3 = (uint32_t)__builtin_amdgcn_ds_bpermute(pidx, (int)packs[qg][2 * ks + 1][1]);
        u32x4 bw = (u32x4){w0, w1, w2, w3};
        pb[qg] = __builtin_bit_cast(f16x8, bw);
      }
      #pragma unroll
      for (int df = 0; df < 4; df++) {
        f16x8 vf = *(const f16x8*)(&Vt[cur][df * 16 + lo4][ks * 32 + hi2 * 8]);
        #pragma unroll
        for (int qg = 0; qg < QG; qg++)
          oacc[qg][df] = MFMA16(vf, pb[qg], oacc[qg][df]);
      }
    }
    // stage next tile into idle buffer, one barrier per tile
    if (t + 1 < NT) {
      #pragma unroll
      for (int i = 0; i < 2; i++) {
        int row = i * 32 + r0;
        *(f16x8*)(&Ks[cur ^ 1][row][c8 * 8]) = kreg[i];
        #pragma unroll
        for (int jj = 0; jj < 8; jj++) Vt[cur ^ 1][c8 * 8 + jj][row] = vreg[i][jj];
      }
    }
    __syncthreads();
    cur ^= 1;
  }

  #pragma unroll
  for (int qg = 0; qg < QG; qg++) {
    float r = lsum[qg];
    r += __shfl_xor(r, 16, 64);
    r += __shfl_xor(r, 32, 64);
    const float invl = 1.0f / r;
    const int orow = qt * (64 * QG) + w * (16 * QG) + qg * 16 + lo4;
    f16* Ob = O + (size_t)(b * NQ + orow) * D_ + h * DH_ + hi2 * 4;
    #pragma unroll
    for (int df = 0; df < 4; df++) {
      f16 t4[4];
      #pragma unroll
      for (int j = 0; j < 4; j++) t4[j] = (f16)(oacc[qg][df][j] * invl);
      *(uint2*)(Ob + df * 16) = *(uint2*)t4;
    }
  }
}

// ---------------------------------------------------------------------------
// Fused residual + LayerNorm, all-f16 I/O (f32 math inside)
// ---------------------------------------------------------------------------
__global__ __launch_bounds__(128) void ln_kernel(
    const f16* __restrict__ a, const f16* __restrict__ r,
    const float* __restrict__ g, const float* __restrict__ be,
    f16* __restrict__ out)
{
  const int row = blockIdx.x;
  const int t = threadIdx.x;
  const f16* ap = a + (size_t)row * D_ + t * 4;
  const f16* rp = r + (size_t)row * D_ + t * 4;
  uint2 au = *(const uint2*)ap, ru = *(const uint2*)rp;
  f16 a4[4], r4[4];
  *(uint2*)a4 = au; *(uint2*)r4 = ru;
  float x0 = (float)a4[0] + (float)r4[0];
  float x1 = (float)a4[1] + (float)r4[1];
  float x2 = (float)a4[2] + (float)r4[2];
  float x3 = (float)a4[3] + (float)r4[3];
  float sm = x0 + x1 + x2 + x3;
  float sq = x0*x0 + x1*x1 + x2*x2 + x3*x3;
  #pragma unroll
  for (int off = 32; off > 0; off >>= 1) {
    sm += __shfl_down(sm, off, 64);
    sq += __shfl_down(sq, off, 64);
  }
  __shared__ float s0[2], s1[2];
  if ((t & 63) == 0) { s0[t >> 6] = sm; s1[t >> 6] = sq; }
  __syncthreads();
  const float Sm = s0[0] + s0[1];
  const float Sq = s1[0] + s1[1];
  const float mean = Sm * (1.0f / 512.0f);
  const float var  = Sq * (1.0f / 512.0f) - mean * mean;
  const float inv  = rsqrtf(var + 1e-5f);
  const float4 vg = *(const float4*)(g + t * 4);
  const float4 vb = *(const float4*)(be + t * 4);
  f16 o4[4];
  o4[0] = (f16)(vg.x * (x0 - mean) * inv + vb.x);
  o4[1] = (f16)(vg.y * (x1 - mean) * inv + vb.y);
  o4[2] = (f16)(vg.z * (x2 - mean) * inv + vb.z);
  o4[3] = (f16)(vg.w * (x3 - mean) * inv + vb.w);
  *(uint2*)(out + (size_t)row * D_ + t * 4) = *(uint2*)o4;
}

// ---------------------------------------------------------------------------
extern "C" void kernel_launch(void* const* d_in, const int* in_sizes, int n_in,
                              void* d_out, int out_size, void* d_ws, size_t ws_size,
                              hipStream_t stream) {
  const int*   bytes_seq = (const int*)  d_in[0];
  const int*   patch_idx = (const int*)  d_in[1];
  const float* byte_emb  = (const float*)d_in[2];
  const float* ngram_emb = (const float*)d_in[3];
  const float* sWq = (const float*)d_in[4];  const float* sbq = (const float*)d_in[5];
  const float* sWk = (const float*)d_in[6];  const float* sbk = (const float*)d_in[7];
  const float* sWv = (const float*)d_in[8];  const float* sbv = (const float*)d_in[9];
  const float* sWo = (const float*)d_in[10]; const float* sbo = (const float*)d_in[11];
  const float* ln1g = (const float*)d_in[12]; const float* ln1b = (const float*)d_in[13];
  const float* W1 = (const float*)d_in[14];  const float* b1 = (const float*)d_in[15];
  const float* W2 = (const float*)d_in[16];  const float* b2 = (const float*)d_in[17];
  const float* ln2g = (const float*)d_in[18]; const float* ln2b = (const float*)d_in[19];
  const float* cWq = (const float*)d_in[20]; const float* cbq = (const float*)d_in[21];
  const float* cWk = (const float*)d_in[22]; const float* cbk = (const float*)d_in[23];
  const float* cWv = (const float*)d_in[24]; const float* cbv = (const float*)d_in[25];
  const float* cWo = (const float*)d_in[26]; const float* cbo = (const float*)d_in[27];

  char* base = (char*)d_ws;
  const size_t MB = 1u << 20;
  f16* E16     = (f16*)(base + 0 * MB);       // 8 MB
  f16* TMP16   = (f16*)(base + 8 * MB);       // 8 MB (ATproj out, FFN2 out)
  f16* X116    = (f16*)(base + 16 * MB);      // 8 MB
  f16* X216    = (f16*)(base + 24 * MB);      // 8 MB
  f16* QKV16   = (f16*)(base + 32 * MB);      // [8192][1536] = 24 MB
  f16* AT16    = (f16*)(base + 56 * MB);      // 8 MB
  f16* HID16   = (f16*)(base + 64 * MB);      // [8192][2048] = 32 MB
  f16* CKV16   = (f16*)(base + 96 * MB);      // [8192][1024] = 16 MB
  f16* CQ16    = (f16*)(base + 112 * MB);     // 1 MB
  f16* CO16    = (f16*)(base + 113 * MB);     // 1 MB
  f16* WT      = (f16*)(base + 114 * MB);     // 8 MB transposed weights
  float* bqkv  = (float*)(base + 123 * MB);   // 1536 f32
  float* bckv  = bqkv + 1536;                 // 1024 f32

  f16* QKVT = WT;                 // [1536][512]: Wq^T | Wk^T | Wv^T
  f16* sWoT = QKVT + 786432;
  f16* W1T  = sWoT + 262144;      // [2048][512]
  f16* W2T  = W1T + 1048576;      // [512][2048]
  f16* cWqT = W2T + 1048576;
  f16* CKVT = cWqT + 262144;      // [1024][512]: cWk^T | cWv^T
  f16* cWoT = CKVT + 524288;

  WJobs wj;
  {
    const float* wsrc[10] = {sWq, sWk, sWv, sWo, W1, W2, cWq, cWk, cWv, cWo};
    f16* wdst[10] = {QKVT, QKVT + 262144, QKVT + 524288, sWoT, W1T, W2T,
                     cWqT, CKVT, CKVT + 262144, cWoT};
    const int wK[10] = {512,512,512,512, 512,2048, 512,512,512,512};
    const int wN[10] = {512,512,512,512, 2048,512, 512,512,512,512};
    for (int i = 0; i < 10; i++) {
      wj.src[i] = wsrc[i]; wj.dst[i] = wdst[i];
      wj.K[i] = wK[i]; wj.N[i] = wN[i];
      wj.tiles[i] = (wK[i] >> 5) * (wN[i] >> 5);
    }
  }

  const dim3 blk256(256), blk128(128);

  wconv_kernel<<<dim3(1024, 10), blk256, 0, stream>>>(wj, sbq, sbk, sbv, cbk, cbv, bqkv, bckv);
  embed_kernel<<<N_, blk128, 0, stream>>>(bytes_seq, byte_emb, ngram_emb, E16);

  // fused QKV projection: [8192][1536]
  gemm_f16<f16, 0, 128><<<dim3(64, 12), blk256, 0, stream>>>(E16, QKVT, bqkv, QKV16, N_, 1536, 512, nullptr);

  // self-attention (Q,K,V strided views into QKV16); 128 q/block
  attn_f16<2><<<512, blk256, 0, stream>>>(QKV16, 1536, QKV16 + 512, QKV16 + 1024, 1536, AT16, S_);

  // output projection (f16) + LN1
  gemm_f16<f16, 0, 64><<<dim3(64, 8), blk256, 0, stream>>>(AT16, sWoT, sbo, TMP16, N_, 512, 512, nullptr);
  ln_kernel<<<N_, blk128, 0, stream>>>(E16, TMP16, ln1g, ln1b, X116);

  // FFN
  gemm_f16<f16, 1, 128><<<dim3(64, 16), blk256, 0, stream>>>(X116, W1T, b1, HID16, N_, 2048, 512, nullptr);
  gemm_f16<f16, 0, 64><<<dim3(64, 8), blk256, 0, stream>>>(HID16, W2T, b2, TMP16, N_, 512, 2048, nullptr);
  ln_kernel<<<N_, blk128, 0, stream>>>(X116, TMP16, ln2g, ln2b, X216);

  // cross attention: fused K|V projection, gather-fused Q projection
  gemm_f16<f16, 0, 128><<<dim3(64, 8), blk256, 0, stream>>>(X216, CKVT, bckv, CKV16, N_, 1024, 512, nullptr);
  gemm_f16<f16, 0, 64><<<dim3(8, 8), blk256, 0, stream>>>(X216, cWqT, cbq, CQ16, NP_, 512, 512, patch_idx);
  attn_f16<1><<<128, blk256, 0, stream>>>(CQ16, 512, CKV16, CKV16 + 512, 1024, CO16, P_);

  // final projection -> d_out (f32)
  gemm_f16<float, 0, 64><<<dim3(8, 8), blk256, 0, stream>>>(CO16, cWoT, cbo, (float*)d_out, NP_, 512, 512, nullptr);
}